// Round 11
// baseline (21239.883 us; speedup 1.0000x reference)
//
#include <hip/hip_runtime.h>

#define NTHR 256
#define NBLK 256   // one block per 2 rows of the 512-wide hidden dims

#define GLOBAL_AS __attribute__((address_space(1)))
#define LDS_AS    __attribute__((address_space(3)))

#define VMCNT0()  asm volatile("s_waitcnt vmcnt(0)" ::: "memory")
#define VMCNT16() asm volatile("s_waitcnt vmcnt(16)" ::: "memory")

__device__ __forceinline__ float sigm_(float z) { return 1.f / (1.f + expf(-z)); }

// ---- producer side: relaxed agent-scope atomic store = write-through to IC ----
__device__ __forceinline__ void coh_store(float* p, float v) {
    __hip_atomic_store(p, v, __ATOMIC_RELAXED, __HIP_MEMORY_SCOPE_AGENT);
}
__device__ __forceinline__ unsigned coh_loadu(const unsigned* p) {
    return __hip_atomic_load(p, __ATOMIC_RELAXED, __HIP_MEMORY_SCOPE_AGENT);
}

// ---- flat barrier: 256 concurrent arrival stores (no RMW chain), wave-parallel poll.
// arr[b] = monotonic epoch of block b. Wave 0 of EVERY block polls all 256 words
// (4/lane, parallel issue ~1 IC round trip) until min >= ep. Tail ~1us vs tree ~3us.
__device__ __forceinline__ void gbar(unsigned* arr, unsigned ep) {
    __syncthreads();
    if (threadIdx.x == 0) {
        asm volatile("s_waitcnt vmcnt(0)" ::: "memory");   // wave-0 coh stores visible at IC
        __hip_atomic_store(arr + blockIdx.x, ep, __ATOMIC_RELAXED, __HIP_MEMORY_SCOPE_AGENT);
    }
    if (threadIdx.x < 64) {
        const unsigned* a4 = arr + threadIdx.x * 4;
        for (;;) {
            unsigned m0 = coh_loadu(a4 + 0);
            unsigned m1 = coh_loadu(a4 + 1);
            unsigned m2 = coh_loadu(a4 + 2);
            unsigned m3 = coh_loadu(a4 + 3);
            bool ok = (m0 >= ep) & (m1 >= ep) & (m2 >= ep) & (m3 >= ep);
            if (__all(ok)) break;
            __builtin_amdgcn_s_sleep(1);
        }
    }
    __syncthreads();
}

// ---- async DMA staging. AUX=17 (sc0|sc1): coherent fetch from IC, bypass L1/L2
// (for cross-block-dynamic hG/dpG/h2G). AUX=0: normal cached (static K/Q). ----
template <int AUX>
__device__ __forceinline__ void stage_dma(const float* __restrict__ src, float (*hb)[516], int tid) {
    const int lane = tid & 63;
    const int wbase = tid - lane;
#pragma unroll
    for (int l = 0; l < 16; ++l) {
        const int e0 = wbase + l * 256;
        const float* g = src + (size_t)(e0 + lane) * 4;
        float* d = &hb[e0 >> 7][(e0 & 127) << 2];
        __builtin_amdgcn_global_load_lds((const GLOBAL_AS unsigned int*)g,
                                         (LDS_AS unsigned int*)d, 16, 0, AUX);
    }
}

// ---------------- projection GEMM: C[n][c] = sum_d A[n][d]*W[c][d] + bias[c] ----------------
__global__ void proj_gemm(const float* __restrict__ A, const float* __restrict__ W,
                          const float* __restrict__ bias, float* __restrict__ C) {
    __shared__ float As[64][33];
    __shared__ float Ws[64][33];
    const int bn = blockIdx.x * 64, bc = blockIdx.y * 64;
    const int tx = threadIdx.x & 15, ty = threadIdx.x >> 4;
    float acc[4][4] = {};
    for (int k0 = 0; k0 < 512; k0 += 32) {
#pragma unroll
        for (int l = 0; l < 2; ++l) {
            int f4 = threadIdx.x + l * 256;
            int row = f4 >> 3;
            int kk = (f4 & 7) << 2;
            float4 av = *(const float4*)&A[(size_t)(bn + row) * 512 + k0 + kk];
            float4 wv = *(const float4*)&W[(size_t)(bc + row) * 512 + k0 + kk];
            As[row][kk] = av.x; As[row][kk + 1] = av.y; As[row][kk + 2] = av.z; As[row][kk + 3] = av.w;
            Ws[row][kk] = wv.x; Ws[row][kk + 1] = wv.y; Ws[row][kk + 2] = wv.z; Ws[row][kk + 3] = wv.w;
        }
        __syncthreads();
#pragma unroll
        for (int kk = 0; kk < 32; ++kk) {
            float a0 = As[ty * 4 + 0][kk], a1 = As[ty * 4 + 1][kk], a2 = As[ty * 4 + 2][kk], a3 = As[ty * 4 + 3][kk];
            float w0 = Ws[tx * 4 + 0][kk], w1 = Ws[tx * 4 + 1][kk], w2 = Ws[tx * 4 + 2][kk], w3 = Ws[tx * 4 + 3][kk];
            acc[0][0] += a0 * w0; acc[0][1] += a0 * w1; acc[0][2] += a0 * w2; acc[0][3] += a0 * w3;
            acc[1][0] += a1 * w0; acc[1][1] += a1 * w1; acc[1][2] += a1 * w2; acc[1][3] += a1 * w3;
            acc[2][0] += a2 * w0; acc[2][1] += a2 * w1; acc[2][2] += a2 * w2; acc[2][3] += a2 * w3;
            acc[3][0] += a3 * w0; acc[3][1] += a3 * w1; acc[3][2] += a3 * w2; acc[3][3] += a3 * w3;
        }
        __syncthreads();
    }
    float4 bvv = *(const float4*)&bias[bc + tx * 4];
#pragma unroll
    for (int i = 0; i < 4; ++i) {
        float4 o = make_float4(acc[i][0] + bvv.x, acc[i][1] + bvv.y, acc[i][2] + bvv.z, acc[i][3] + bvv.w);
        *(float4*)&C[(size_t)(bn + ty * 4 + i) * 512 + bc + tx * 4] = o;
    }
}

// ---------------- depthwise conv over S (K=3, pad=1) + channel bias ----------------
__global__ void conv_kernel(const float* __restrict__ P, const float* __restrict__ cw,
                            const float* __restrict__ cb, float* __restrict__ O) {
    int idx = blockIdx.x * 256 + threadIdx.x;
    if (idx >= 1024 * 32 * 128) return;
    int c4 = (idx & 127) << 2;
    int sb = idx >> 7;
    int s = sb >> 5, b = sb & 31;
    float acc0 = cb[c4 + 0], acc1 = cb[c4 + 1], acc2 = cb[c4 + 2], acc3 = cb[c4 + 3];
#pragma unroll
    for (int d = 0; d < 3; ++d) {
        int s2 = s + d - 1;
        if (s2 < 0 || s2 >= 1024) continue;
        float4 pv = *(const float4*)&P[((size_t)s2 * 32 + b) * 512 + c4];
        acc0 += pv.x * cw[(c4 + 0) * 3 + d];
        acc1 += pv.y * cw[(c4 + 1) * 3 + d];
        acc2 += pv.z * cw[(c4 + 2) * 3 + d];
        acc3 += pv.w * cw[(c4 + 3) * 3 + d];
    }
    *(float4*)&O[(size_t)sb * 512 + c4] = make_float4(acc0, acc1, acc2, acc3);
}

// ---------------- per-step scalars: alpha/eta/theta ----------------
__global__ void scalars_kernel(const float* __restrict__ x,
                               const float* __restrict__ aw, const float* __restrict__ ab,
                               const float* __restrict__ ew, const float* __restrict__ eb,
                               const float* __restrict__ tw, const float* __restrict__ tb,
                               float* __restrict__ scal) {
    const int t = blockIdx.x, tid = threadIdx.x;
    const int b = tid >> 3, part = tid & 7;
    const float* xp = x + ((size_t)t * 32 + b) * 512 + part * 64;
    float sa = 0.f, se = 0.f, st = 0.f;
    for (int i = 0; i < 64; i += 4) {
        float4 xv = *(const float4*)&xp[i];
        float4 av = *(const float4*)&aw[part * 64 + i];
        float4 ev = *(const float4*)&ew[part * 64 + i];
        float4 tv = *(const float4*)&tw[part * 64 + i];
        sa += xv.x * av.x + xv.y * av.y + xv.z * av.z + xv.w * av.w;
        se += xv.x * ev.x + xv.y * ev.y + xv.z * ev.z + xv.w * ev.w;
        st += xv.x * tv.x + xv.y * tv.y + xv.z * tv.z + xv.w * tv.w;
    }
#pragma unroll
    for (int m = 1; m < 8; m <<= 1) {
        sa += __shfl_xor(sa, m);
        se += __shfl_xor(se, m);
        st += __shfl_xor(st, m);
    }
    __shared__ float ra[32], re[32], rt[32];
    if (part == 0) {
        ra[b] = sigm_(sa + ab[0]);
        re[b] = sigm_(se + eb[0]);
        float z = st + tb[0];
        rt[b] = fmaxf(z, 0.f) + log1pf(expf(-fabsf(z)));
    }
    __syncthreads();
    if (tid == 0) { float s = 0.f; for (int i = 0; i < 32; ++i) s += ra[i]; scal[t] = s / 32.f; }
    if (tid == 1) { float s = 0.f; for (int i = 0; i < 32; ++i) s += re[i]; scal[1024 + t] = s / 32.f; }
    if (tid == 2) { float s = 0.f; for (int i = 0; i < 32; ++i) s += rt[i]; scal[2048 + t] = s / 32.f; }
}

// ---------------- in-place row l2-normalize of K and Q ----------------
__global__ void l2norm_kernel(float* __restrict__ Kb, float* __restrict__ Qb) {
    int w = (blockIdx.x * 256 + threadIdx.x) >> 6;
    int lane = threadIdx.x & 63;
    if (w >= 2 * 32768) return;
    float* row = (w < 32768) ? (Kb + (size_t)w * 512) : (Qb + (size_t)(w - 32768) * 512);
    float4 v0 = *(float4*)&row[lane * 8];
    float4 v1 = *(float4*)&row[lane * 8 + 4];
    float ss = v0.x * v0.x + v0.y * v0.y + v0.z * v0.z + v0.w * v0.w
             + v1.x * v1.x + v1.y * v1.y + v1.z * v1.z + v1.w * v1.w;
#pragma unroll
    for (int m = 1; m < 64; m <<= 1) ss += __shfl_xor(ss, m);
    float inv = 1.f / fmaxf(sqrtf(ss), 1e-12f);
    v0.x *= inv; v0.y *= inv; v0.z *= inv; v0.w *= inv;
    v1.x *= inv; v1.y *= inv; v1.z *= inv; v1.w *= inv;
    *(float4*)&row[lane * 8] = v0;
    *(float4*)&row[lane * 8 + 4] = v1;
}

// ---------------- the sequential TTT scan (double-buffered coherent DMA staging) ----------------
__global__ void __launch_bounds__(NTHR, 1) scan_kernel(
    const float* __restrict__ Kn, const float* __restrict__ Vv, const float* __restrict__ Qn,
    const float* __restrict__ scal,
    const float* __restrict__ MW1_0, const float* __restrict__ Mb1_0,
    const float* __restrict__ MW2_0, const float* __restrict__ Mb2_0,
    float* __restrict__ hG, float* __restrict__ dpG, float* __restrict__ h2G,
    float* __restrict__ outp, unsigned* __restrict__ bar) {
    const int g = blockIdx.x;
    const int tid = threadIdx.x;
    const int j0 = g * 2;
    unsigned ep = 0;

    __shared__ float W1[2][512], SW1[2][512];
    __shared__ float W2[2][512], SW2[2][512];
    __shared__ float W2T[2][512], SW2T[2][512];
    __shared__ float hbuf[32][516];                 // buffer A
    __shared__ float buf2[32][516];                 // buffer B (double-buffer)
    __shared__ float red[4][32][2], red2[4][32][2];
    __shared__ float dpl[32][2], dzl[32][2], hj[32][2], hjp[32][2];
    __shared__ float bv1[2], Sb1[2], bv2[2], Sb2[2];

    for (int r = 0; r < 2; ++r) {
        for (int c = tid; c < 512; c += NTHR) {
            W1[r][c] = MW1_0[(size_t)(j0 + r) * 512 + c];
            W2[r][c] = MW2_0[(size_t)(j0 + r) * 512 + c];
            W2T[r][c] = MW2_0[(size_t)c * 512 + (j0 + r)];
            SW1[r][c] = 0.f; SW2[r][c] = 0.f; SW2T[r][c] = 0.f;
        }
    }
    if (tid < 2) { bv1[tid] = Mb1_0[j0 + tid]; Sb1[tid] = 0.f; bv2[tid] = Mb2_0[j0 + tid]; Sb2[tid] = 0.f; }
    __syncthreads();
    // h(0) = silu(ktn(0) @ W1.T + b1), owned slice
    {
        const int b = tid & 31, r = (tid >> 5) & 1, q = tid >> 6;
        const float* kt = Kn + (size_t)b * 512;
        float p = 0.f;
        for (int i = q * 128; i < q * 128 + 128; i += 4) {
            float4 kv = *(const float4*)&kt[i];
            p += kv.x * W1[r][i] + kv.y * W1[r][i + 1] + kv.z * W1[r][i + 2] + kv.w * W1[r][i + 3];
        }
        red[q][b][r] = p;
    }
    __syncthreads();
    if (tid < 64) {
        const int b = tid & 31, r = tid >> 5;
        float z = red[0][b][r] + red[1][b][r] + red[2][b][r] + red[3][b][r] + bv1[r];
        hjp[b][r] = z;
        float hh = z * sigm_(z);
        hj[b][r] = hh;
        coh_store(&hG[b * 512 + j0 + r], hh);
    }
    gbar(bar, ++ep);

    for (int t = 0; t < 1024; ++t) {
        const float alpha = scal[t], eta = scal[1024 + t], theta = scal[2048 + t];
        // ======== phase A ========
        float vpre = 0.f;
        if (tid < 64) vpre = Vv[((size_t)t * 32 + (tid & 31)) * 512 + j0 + (tid >> 5)];
        stage_dma<17>(hG, hbuf, tid);               // h(t)  -> A (coherent)
        stage_dma<17>(h2G, buf2, tid);              // h2(t-1) -> B (coherent; garbage at t=0, unused)
        VMCNT0(); __syncthreads();
        {
            const int b = tid & 31, q = (tid >> 5) & 3, half = tid >> 7;
            float p0 = 0.f, p1 = 0.f;
            if (half == 0) {
                for (int j = q * 128; j < q * 128 + 128; j += 4) {
                    float4 hv = *(const float4*)&hbuf[b][j];
                    p0 += hv.x * W2[0][j] + hv.y * W2[0][j + 1] + hv.z * W2[0][j + 2] + hv.w * W2[0][j + 3];
                    p1 += hv.x * W2[1][j] + hv.y * W2[1][j + 1] + hv.z * W2[1][j + 2] + hv.w * W2[1][j + 3];
                }
                red[q][b][0] = p0; red[q][b][1] = p1;
            } else if (t > 0) {
                for (int j = q * 128; j < q * 128 + 128; j += 4) {
                    float4 hv = *(const float4*)&buf2[b][j];
                    p0 += hv.x * W2[0][j] + hv.y * W2[0][j + 1] + hv.z * W2[0][j + 2] + hv.w * W2[0][j + 3];
                    p1 += hv.x * W2[1][j] + hv.y * W2[1][j + 1] + hv.z * W2[1][j + 2] + hv.w * W2[1][j + 3];
                }
                red2[q][b][0] = p0; red2[q][b][1] = p1;
            }
        }
        __syncthreads();
        if (tid < 64) {
            const int b = tid & 31, o = tid >> 5;
            float pred = red[0][b][o] + red[1][b][o] + red[2][b][o] + red[3][b][o] + bv2[o];
            float dp = (pred - vpre) * (2.f / 16384.f);
            dpl[b][o] = dp;
            coh_store(&dpG[b * 512 + j0 + o], dp);
        } else if (tid < 128) {
            if (t > 0) {
                const int b = tid & 31, o = (tid >> 5) & 1;
                float ov = red2[0][b][o] + red2[1][b][o] + red2[2][b][o] + red2[3][b][o] + bv2[o];
                outp[((size_t)(t - 1) * 32 + b) * 512 + j0 + o] = ov;
            }
        }
        __syncthreads();
        if (tid < 2) {
            float db2 = 0.f;
            for (int b = 0; b < 32; ++b) db2 += dpl[b][tid];
            float s = eta * Sb2[tid] - theta * db2;
            Sb2[tid] = s;
            bv2[tid] = (1.f - alpha) * bv2[tid] + s;
        }
        {
            const int j = tid * 2;
            float d00 = 0.f, d01 = 0.f, d10 = 0.f, d11 = 0.f;
            for (int b = 0; b < 32; ++b) {
                float h0 = hbuf[b][j], h1 = hbuf[b][j + 1];
                float q0 = dpl[b][0], q1 = dpl[b][1];
                d00 += q0 * h0; d01 += q0 * h1; d10 += q1 * h0; d11 += q1 * h1;
            }
            float s;
            s = eta * SW2[0][j] - theta * d00;     SW2[0][j] = s;     W2[0][j]     = (1.f - alpha) * W2[0][j] + s;
            s = eta * SW2[0][j + 1] - theta * d01; SW2[0][j + 1] = s; W2[0][j + 1] = (1.f - alpha) * W2[0][j + 1] + s;
            s = eta * SW2[1][j] - theta * d10;     SW2[1][j] = s;     W2[1][j]     = (1.f - alpha) * W2[1][j] + s;
            s = eta * SW2[1][j + 1] - theta * d11; SW2[1][j + 1] = s; W2[1][j + 1] = (1.f - alpha) * W2[1][j + 1] + s;
        }
        gbar(bar, ++ep);

        // ======== phase B (pipelined: K under dh/dW2T, Q under dW1, K2 under GEMM4) ========
        stage_dma<17>(dpG, hbuf, tid);              // dp -> A (coherent)
        stage_dma<0>(Kn + (size_t)t * 16384, buf2, tid);   // K(t) -> B (cached)
        VMCNT16(); __syncthreads();                 // dp(A) ready, K still flying
        {
            const int b = tid & 31, r = (tid >> 5) & 1, q = tid >> 6;
            float p = 0.f;
            for (int o = q * 128; o < q * 128 + 128; o += 4) {
                float4 dv = *(const float4*)&hbuf[b][o];
                p += dv.x * W2T[r][o] + dv.y * W2T[r][o + 1] + dv.z * W2T[r][o + 2] + dv.w * W2T[r][o + 3];
            }
            red[q][b][r] = p;
        }
        __syncthreads();
        if (tid < 64) {
            const int b = tid & 31, r = tid >> 5;
            float dh = red[0][b][r] + red[1][b][r] + red[2][b][r] + red[3][b][r];
            float z = hjp[b][r];
            float sg = sigm_(z);
            dzl[b][r] = dh * (sg * (1.f + z * (1.f - sg)));
        }
        __syncthreads();
        if (tid < 2) {
            float db1 = 0.f;
            for (int b = 0; b < 32; ++b) db1 += dzl[b][tid];
            float s = eta * Sb1[tid] - theta * db1;
            Sb1[tid] = s;
            bv1[tid] = (1.f - alpha) * bv1[tid] + s;
        }
        {
            const int o = tid * 2;
            float d00 = 0.f, d01 = 0.f, d10 = 0.f, d11 = 0.f;
            for (int b = 0; b < 32; ++b) {
                float q0 = hbuf[b][o], q1 = hbuf[b][o + 1];
                float h0 = hj[b][0], h1 = hj[b][1];
                d00 += h0 * q0; d01 += h0 * q1; d10 += h1 * q0; d11 += h1 * q1;
            }
            float s;
            s = eta * SW2T[0][o] - theta * d00;     SW2T[0][o] = s;     W2T[0][o]     = (1.f - alpha) * W2T[0][o] + s;
            s = eta * SW2T[0][o + 1] - theta * d01; SW2T[0][o + 1] = s; W2T[0][o + 1] = (1.f - alpha) * W2T[0][o + 1] + s;
            s = eta * SW2T[1][o] - theta * d10;     SW2T[1][o] = s;     W2T[1][o]     = (1.f - alpha) * W2T[1][o] + s;
            s = eta * SW2T[1][o + 1] - theta * d11; SW2T[1][o + 1] = s; W2T[1][o + 1] = (1.f - alpha) * W2T[1][o + 1] + s;
        }
        __syncthreads();                            // all reads of A done
        stage_dma<0>(Qn + (size_t)t * 16384, hbuf, tid);   // Q(t) -> A (cached)
        VMCNT16(); __syncthreads();                 // K(B) ready, Q still flying
        {
            const int c = tid * 2;
            float d00 = 0.f, d01 = 0.f, d10 = 0.f, d11 = 0.f;
            for (int b = 0; b < 32; ++b) {
                float k0 = buf2[b][c], k1 = buf2[b][c + 1];
                float z0 = dzl[b][0], z1 = dzl[b][1];
                d00 += z0 * k0; d01 += z0 * k1; d10 += z1 * k0; d11 += z1 * k1;
            }
            float s;
            s = eta * SW1[0][c] - theta * d00;     SW1[0][c] = s;     W1[0][c]     = (1.f - alpha) * W1[0][c] + s;
            s = eta * SW1[0][c + 1] - theta * d01; SW1[0][c + 1] = s; W1[0][c + 1] = (1.f - alpha) * W1[0][c + 1] + s;
            s = eta * SW1[1][c] - theta * d10;     SW1[1][c] = s;     W1[1][c]     = (1.f - alpha) * W1[1][c] + s;
            s = eta * SW1[1][c + 1] - theta * d11; SW1[1][c + 1] = s; W1[1][c + 1] = (1.f - alpha) * W1[1][c + 1] + s;
        }
        __syncthreads();                            // all reads of B done
        if (t < 1023) {
            stage_dma<0>(Kn + (size_t)(t + 1) * 16384, buf2, tid);  // K(t+1) -> B
            VMCNT16();                              // Q(A) ready, K2 still flying
        } else {
            VMCNT0();                               // Q(A) ready
        }
        __syncthreads();
        {
            const int b = tid & 31, r = (tid >> 5) & 1, q = tid >> 6;
            float p = 0.f;
            for (int i = q * 128; i < q * 128 + 128; i += 4) {
                float4 qv2 = *(const float4*)&hbuf[b][i];
                p += qv2.x * W1[r][i] + qv2.y * W1[r][i + 1] + qv2.z * W1[r][i + 2] + qv2.w * W1[r][i + 3];
            }
            red[q][b][r] = p;
        }
        __syncthreads();
        VMCNT0(); __syncthreads();                  // K2(B) ready
        if (t < 1023) {
            const int b = tid & 31, r = (tid >> 5) & 1, q = tid >> 6;
            float p = 0.f;
            for (int i = q * 128; i < q * 128 + 128; i += 4) {
                float4 kv2 = *(const float4*)&buf2[b][i];
                p += kv2.x * W1[r][i] + kv2.y * W1[r][i + 1] + kv2.z * W1[r][i + 2] + kv2.w * W1[r][i + 3];
            }
            red2[q][b][r] = p;
        }
        __syncthreads();
        if (tid < 64) {
            const int b = tid & 31, r = tid >> 5;
            float z2 = red[0][b][r] + red[1][b][r] + red[2][b][r] + red[3][b][r] + bv1[r];
            coh_store(&h2G[b * 512 + j0 + r], z2 * sigm_(z2));
            if (t < 1023) {
                float z = red2[0][b][r] + red2[1][b][r] + red2[2][b][r] + red2[3][b][r] + bv1[r];
                hjp[b][r] = z;
                float hh = z * sigm_(z);
                hj[b][r] = hh;
                coh_store(&hG[b * 512 + j0 + r], hh);
            }
        }
        gbar(bar, ++ep);
    }

    // ---- epilogue: out[1023] = h2(1023) @ W2(1023).T + b2(1023) ----
    stage_dma<17>(h2G, hbuf, tid);
    VMCNT0(); __syncthreads();
    {
        const int b = tid & 31, q = (tid >> 5) & 3, half = tid >> 7;
        if (half == 0) {
            float p0 = 0.f, p1 = 0.f;
            for (int j = q * 128; j < q * 128 + 128; j += 4) {
                float4 hv = *(const float4*)&hbuf[b][j];
                p0 += hv.x * W2[0][j] + hv.y * W2[0][j + 1] + hv.z * W2[0][j + 2] + hv.w * W2[0][j + 3];
                p1 += hv.x * W2[1][j] + hv.y * W2[1][j + 1] + hv.z * W2[1][j + 2] + hv.w * W2[1][j + 3];
            }
            red[q][b][0] = p0; red[q][b][1] = p1;
        }
        __syncthreads();
        if (tid < 64) {
            const int b = tid & 31, o = tid >> 5;
            float ov = red[0][b][o] + red[1][b][o] + red[2][b][o] + red[3][b][o] + bv2[o];
            outp[((size_t)1023 * 32 + b) * 512 + j0 + o] = ov;
        }
    }
}

extern "C" void kernel_launch(void* const* d_in, const int* in_sizes, int n_in,
                              void* d_out, int out_size, void* d_ws, size_t ws_size,
                              hipStream_t stream) {
    (void)in_sizes; (void)n_in; (void)out_size; (void)ws_size;
    const float* x    = (const float*)d_in[0];
    const float* Wk_w = (const float*)d_in[1];
    const float* Wk_b = (const float*)d_in[2];
    const float* Wv_w = (const float*)d_in[3];
    const float* Wv_b = (const float*)d_in[4];
    const float* Wq_w = (const float*)d_in[5];
    const float* Wq_b = (const float*)d_in[6];
    const float* ck_w = (const float*)d_in[7];
    const float* ck_b = (const float*)d_in[8];
    const float* cv_w = (const float*)d_in[9];
    const float* cv_b = (const float*)d_in[10];
    const float* cq_w = (const float*)d_in[11];
    const float* cq_b = (const float*)d_in[12];
    const float* MW1  = (const float*)d_in[13];
    const float* Mb1  = (const float*)d_in[14];
    const float* MW2  = (const float*)d_in[15];
    const float* Mb2  = (const float*)d_in[16];
    const float* a_w  = (const float*)d_in[17];
    const float* a_b  = (const float*)d_in[18];
    const float* e_w  = (const float*)d_in[19];
    const float* e_b  = (const float*)d_in[20];
    const float* t_w  = (const float*)d_in[21];
    const float* t_b  = (const float*)d_in[22];

    float* out = (float*)d_out;
    float* ws = (float*)d_ws;
    float* Kb   = ws;                    // [1024][32][512]
    float* Vb   = Kb + 16777216;
    float* Qb   = Vb + 16777216;
    float* scal = Qb + 16777216;         // [3][1024]
    float* hG   = scal + 3072;           // [32][512]
    float* dpG  = hG + 16384;
    float* h2G  = dpG + 16384;
    unsigned* bar = (unsigned*)(h2G + 16384);  // arr[256] arrivals; memset 8KB
    float* tmp  = out;                   // reuse d_out as pre-conv scratch

    hipMemsetAsync(bar, 0, 8192, stream);
    scalars_kernel<<<1024, 256, 0, stream>>>(x, a_w, a_b, e_w, e_b, t_w, t_b, scal);
    proj_gemm<<<dim3(512, 8), 256, 0, stream>>>(x, Wk_w, Wk_b, tmp);
    conv_kernel<<<16384, 256, 0, stream>>>(tmp, ck_w, ck_b, Kb);
    proj_gemm<<<dim3(512, 8), 256, 0, stream>>>(x, Wv_w, Wv_b, tmp);
    conv_kernel<<<16384, 256, 0, stream>>>(tmp, cv_w, cv_b, Vb);
    proj_gemm<<<dim3(512, 8), 256, 0, stream>>>(x, Wq_w, Wq_b, tmp);
    conv_kernel<<<16384, 256, 0, stream>>>(tmp, cq_w, cq_b, Qb);
    l2norm_kernel<<<16384, 256, 0, stream>>>(Kb, Qb);

    const float *aKn = Kb, *aV = Vb, *aQn = Qb, *aSc = scal;
    const float *aW1 = MW1, *ab1 = Mb1, *aW2 = MW2, *ab2 = Mb2;
    float *ahG = hG, *adpG = dpG, *ah2G = h2G, *aout = out;
    unsigned* abar = bar;
    void* kargs[] = {(void*)&aKn, (void*)&aV, (void*)&aQn, (void*)&aSc,
                     (void*)&aW1, (void*)&ab1, (void*)&aW2, (void*)&ab2,
                     (void*)&ahG, (void*)&adpG, (void*)&ah2G, (void*)&aout, (void*)&abar};
    hipError_t ce = hipLaunchCooperativeKernel((void*)scan_kernel, dim3(NBLK), dim3(NTHR), kargs, 0, stream);
    if (ce != hipSuccess) {
        // Cooperative validation rejected the kernel; our barrier only needs co-residency
        // (grid == 256 CUs, 160KB LDS forces 1 block/CU), so fall back to a regular launch.
        scan_kernel<<<dim3(NBLK), dim3(NTHR), 0, stream>>>(
            Kb, Vb, Qb, scal, MW1, Mb1, MW2, Mb2, hG, dpG, h2G, out, bar);
    }
}

// Round 12
// 15826.707 us; speedup vs baseline: 1.3420x; 1.3420x over previous
//
#include <hip/hip_runtime.h>

#define NTHR 256
#define NBLK 256   // one block per 2 rows of the 512-wide hidden dims

#define GLOBAL_AS __attribute__((address_space(1)))
#define LDS_AS    __attribute__((address_space(3)))

#define VMCNT0()  asm volatile("s_waitcnt vmcnt(0)" ::: "memory")
#define VMCNT16() asm volatile("s_waitcnt vmcnt(16)" ::: "memory")

__device__ __forceinline__ float sigm_(float z) { return 1.f / (1.f + expf(-z)); }

// ---- producer side: relaxed agent-scope atomic store = write-through to IC ----
__device__ __forceinline__ void coh_store(float* p, float v) {
    __hip_atomic_store(p, v, __ATOMIC_RELAXED, __HIP_MEMORY_SCOPE_AGENT);
}
__device__ __forceinline__ unsigned coh_loadu(const unsigned* p) {
    return __hip_atomic_load(p, __ATOMIC_RELAXED, __HIP_MEMORY_SCOPE_AGENT);
}

// ---- hybrid barrier: flat concurrent arrival stores (no RMW chain) +
// SINGLE-poller detection (block 0 wave 0 polls arr[256]; round-11 lesson:
// all-blocks-poll congests the IC lines and regresses) + one-flag broadcast.
__device__ __forceinline__ void gbar(unsigned* arr, unsigned ep) {
    __syncthreads();
    if (threadIdx.x == 0) {
        asm volatile("s_waitcnt vmcnt(0)" ::: "memory");   // wave-0 coh stores visible at IC
        __hip_atomic_store(arr + blockIdx.x, ep, __ATOMIC_RELAXED, __HIP_MEMORY_SCOPE_AGENT);
    }
    if (blockIdx.x == 0) {
        if (threadIdx.x < 64) {
            const unsigned* a4 = arr + threadIdx.x * 4;
            for (;;) {
                unsigned m0 = coh_loadu(a4 + 0);
                unsigned m1 = coh_loadu(a4 + 1);
                unsigned m2 = coh_loadu(a4 + 2);
                unsigned m3 = coh_loadu(a4 + 3);
                bool ok = (m0 >= ep) & (m1 >= ep) & (m2 >= ep) & (m3 >= ep);
                if (__all(ok)) break;
                __builtin_amdgcn_s_sleep(1);
            }
            if (threadIdx.x == 0)
                __hip_atomic_store(arr + 320, ep, __ATOMIC_RELAXED, __HIP_MEMORY_SCOPE_AGENT);
        }
    } else if (threadIdx.x == 0) {
        while (coh_loadu(arr + 320) < ep) __builtin_amdgcn_s_sleep(1);
    }
    __syncthreads();
}

// ---- async DMA staging. AUX=17 (sc0|sc1): coherent fetch from IC, bypass L1/L2
// (for cross-block-dynamic hG/dpG/h2G). AUX=0: normal cached (static K/Q). ----
template <int AUX>
__device__ __forceinline__ void stage_dma(const float* __restrict__ src, float (*hb)[516], int tid) {
    const int lane = tid & 63;
    const int wbase = tid - lane;
#pragma unroll
    for (int l = 0; l < 16; ++l) {
        const int e0 = wbase + l * 256;
        const float* g = src + (size_t)(e0 + lane) * 4;
        float* d = &hb[e0 >> 7][(e0 & 127) << 2];
        __builtin_amdgcn_global_load_lds((const GLOBAL_AS unsigned int*)g,
                                         (LDS_AS unsigned int*)d, 16, 0, AUX);
    }
}

// ---------------- projection GEMM: C[n][c] = sum_d A[n][d]*W[c][d] + bias[c] ----------------
__global__ void proj_gemm(const float* __restrict__ A, const float* __restrict__ W,
                          const float* __restrict__ bias, float* __restrict__ C) {
    __shared__ float As[64][33];
    __shared__ float Ws[64][33];
    const int bn = blockIdx.x * 64, bc = blockIdx.y * 64;
    const int tx = threadIdx.x & 15, ty = threadIdx.x >> 4;
    float acc[4][4] = {};
    for (int k0 = 0; k0 < 512; k0 += 32) {
#pragma unroll
        for (int l = 0; l < 2; ++l) {
            int f4 = threadIdx.x + l * 256;
            int row = f4 >> 3;
            int kk = (f4 & 7) << 2;
            float4 av = *(const float4*)&A[(size_t)(bn + row) * 512 + k0 + kk];
            float4 wv = *(const float4*)&W[(size_t)(bc + row) * 512 + k0 + kk];
            As[row][kk] = av.x; As[row][kk + 1] = av.y; As[row][kk + 2] = av.z; As[row][kk + 3] = av.w;
            Ws[row][kk] = wv.x; Ws[row][kk + 1] = wv.y; Ws[row][kk + 2] = wv.z; Ws[row][kk + 3] = wv.w;
        }
        __syncthreads();
#pragma unroll
        for (int kk = 0; kk < 32; ++kk) {
            float a0 = As[ty * 4 + 0][kk], a1 = As[ty * 4 + 1][kk], a2 = As[ty * 4 + 2][kk], a3 = As[ty * 4 + 3][kk];
            float w0 = Ws[tx * 4 + 0][kk], w1 = Ws[tx * 4 + 1][kk], w2 = Ws[tx * 4 + 2][kk], w3 = Ws[tx * 4 + 3][kk];
            acc[0][0] += a0 * w0; acc[0][1] += a0 * w1; acc[0][2] += a0 * w2; acc[0][3] += a0 * w3;
            acc[1][0] += a1 * w0; acc[1][1] += a1 * w1; acc[1][2] += a1 * w2; acc[1][3] += a1 * w3;
            acc[2][0] += a2 * w0; acc[2][1] += a2 * w1; acc[2][2] += a2 * w2; acc[2][3] += a2 * w3;
            acc[3][0] += a3 * w0; acc[3][1] += a3 * w1; acc[3][2] += a3 * w2; acc[3][3] += a3 * w3;
        }
        __syncthreads();
    }
    float4 bvv = *(const float4*)&bias[bc + tx * 4];
#pragma unroll
    for (int i = 0; i < 4; ++i) {
        float4 o = make_float4(acc[i][0] + bvv.x, acc[i][1] + bvv.y, acc[i][2] + bvv.z, acc[i][3] + bvv.w);
        *(float4*)&C[(size_t)(bn + ty * 4 + i) * 512 + bc + tx * 4] = o;
    }
}

// ---------------- depthwise conv over S (K=3, pad=1) + channel bias ----------------
__global__ void conv_kernel(const float* __restrict__ P, const float* __restrict__ cw,
                            const float* __restrict__ cb, float* __restrict__ O) {
    int idx = blockIdx.x * 256 + threadIdx.x;
    if (idx >= 1024 * 32 * 128) return;
    int c4 = (idx & 127) << 2;
    int sb = idx >> 7;
    int s = sb >> 5, b = sb & 31;
    float acc0 = cb[c4 + 0], acc1 = cb[c4 + 1], acc2 = cb[c4 + 2], acc3 = cb[c4 + 3];
#pragma unroll
    for (int d = 0; d < 3; ++d) {
        int s2 = s + d - 1;
        if (s2 < 0 || s2 >= 1024) continue;
        float4 pv = *(const float4*)&P[((size_t)s2 * 32 + b) * 512 + c4];
        acc0 += pv.x * cw[(c4 + 0) * 3 + d];
        acc1 += pv.y * cw[(c4 + 1) * 3 + d];
        acc2 += pv.z * cw[(c4 + 2) * 3 + d];
        acc3 += pv.w * cw[(c4 + 3) * 3 + d];
    }
    *(float4*)&O[(size_t)sb * 512 + c4] = make_float4(acc0, acc1, acc2, acc3);
}

// ---------------- per-step scalars: alpha/eta/theta ----------------
__global__ void scalars_kernel(const float* __restrict__ x,
                               const float* __restrict__ aw, const float* __restrict__ ab,
                               const float* __restrict__ ew, const float* __restrict__ eb,
                               const float* __restrict__ tw, const float* __restrict__ tb,
                               float* __restrict__ scal) {
    const int t = blockIdx.x, tid = threadIdx.x;
    const int b = tid >> 3, part = tid & 7;
    const float* xp = x + ((size_t)t * 32 + b) * 512 + part * 64;
    float sa = 0.f, se = 0.f, st = 0.f;
    for (int i = 0; i < 64; i += 4) {
        float4 xv = *(const float4*)&xp[i];
        float4 av = *(const float4*)&aw[part * 64 + i];
        float4 ev = *(const float4*)&ew[part * 64 + i];
        float4 tv = *(const float4*)&tw[part * 64 + i];
        sa += xv.x * av.x + xv.y * av.y + xv.z * av.z + xv.w * av.w;
        se += xv.x * ev.x + xv.y * ev.y + xv.z * ev.z + xv.w * ev.w;
        st += xv.x * tv.x + xv.y * tv.y + xv.z * tv.z + xv.w * tv.w;
    }
#pragma unroll
    for (int m = 1; m < 8; m <<= 1) {
        sa += __shfl_xor(sa, m);
        se += __shfl_xor(se, m);
        st += __shfl_xor(st, m);
    }
    __shared__ float ra[32], re[32], rt[32];
    if (part == 0) {
        ra[b] = sigm_(sa + ab[0]);
        re[b] = sigm_(se + eb[0]);
        float z = st + tb[0];
        rt[b] = fmaxf(z, 0.f) + log1pf(expf(-fabsf(z)));
    }
    __syncthreads();
    if (tid == 0) { float s = 0.f; for (int i = 0; i < 32; ++i) s += ra[i]; scal[t] = s / 32.f; }
    if (tid == 1) { float s = 0.f; for (int i = 0; i < 32; ++i) s += re[i]; scal[1024 + t] = s / 32.f; }
    if (tid == 2) { float s = 0.f; for (int i = 0; i < 32; ++i) s += rt[i]; scal[2048 + t] = s / 32.f; }
}

// ---------------- in-place row l2-normalize of K and Q ----------------
__global__ void l2norm_kernel(float* __restrict__ Kb, float* __restrict__ Qb) {
    int w = (blockIdx.x * 256 + threadIdx.x) >> 6;
    int lane = threadIdx.x & 63;
    if (w >= 2 * 32768) return;
    float* row = (w < 32768) ? (Kb + (size_t)w * 512) : (Qb + (size_t)(w - 32768) * 512);
    float4 v0 = *(float4*)&row[lane * 8];
    float4 v1 = *(float4*)&row[lane * 8 + 4];
    float ss = v0.x * v0.x + v0.y * v0.y + v0.z * v0.z + v0.w * v0.w
             + v1.x * v1.x + v1.y * v1.y + v1.z * v1.z + v1.w * v1.w;
#pragma unroll
    for (int m = 1; m < 64; m <<= 1) ss += __shfl_xor(ss, m);
    float inv = 1.f / fmaxf(sqrtf(ss), 1e-12f);
    v0.x *= inv; v0.y *= inv; v0.z *= inv; v0.w *= inv;
    v1.x *= inv; v1.y *= inv; v1.z *= inv; v1.w *= inv;
    *(float4*)&row[lane * 8] = v0;
    *(float4*)&row[lane * 8 + 4] = v1;
}

// ---------------- the sequential TTT scan (double-buffered coherent DMA staging) ----------------
__global__ void __launch_bounds__(NTHR, 1) scan_kernel(
    const float* __restrict__ Kn, const float* __restrict__ Vv, const float* __restrict__ Qn,
    const float* __restrict__ scal,
    const float* __restrict__ MW1_0, const float* __restrict__ Mb1_0,
    const float* __restrict__ MW2_0, const float* __restrict__ Mb2_0,
    float* __restrict__ hG, float* __restrict__ dpG, float* __restrict__ h2G,
    float* __restrict__ outp, unsigned* __restrict__ bar) {
    const int g = blockIdx.x;
    const int tid = threadIdx.x;
    const int j0 = g * 2;
    unsigned ep = 0;

    __shared__ float W1[2][512], SW1[2][512];
    __shared__ float W2[2][512], SW2[2][512];
    __shared__ float W2T[2][512], SW2T[2][512];
    __shared__ float hbuf[32][516];                 // buffer A
    __shared__ float buf2[32][516];                 // buffer B (double-buffer)
    __shared__ float red[4][32][2], red2[4][32][2];
    __shared__ float dpl[32][2], dzl[32][2], hj[32][2], hjp[32][2];
    __shared__ float bv1[2], Sb1[2], bv2[2], Sb2[2];

    for (int r = 0; r < 2; ++r) {
        for (int c = tid; c < 512; c += NTHR) {
            W1[r][c] = MW1_0[(size_t)(j0 + r) * 512 + c];
            W2[r][c] = MW2_0[(size_t)(j0 + r) * 512 + c];
            W2T[r][c] = MW2_0[(size_t)c * 512 + (j0 + r)];
            SW1[r][c] = 0.f; SW2[r][c] = 0.f; SW2T[r][c] = 0.f;
        }
    }
    if (tid < 2) { bv1[tid] = Mb1_0[j0 + tid]; Sb1[tid] = 0.f; bv2[tid] = Mb2_0[j0 + tid]; Sb2[tid] = 0.f; }
    __syncthreads();
    // h(0) = silu(ktn(0) @ W1.T + b1), owned slice
    {
        const int b = tid & 31, r = (tid >> 5) & 1, q = tid >> 6;
        const float* kt = Kn + (size_t)b * 512;
        float p = 0.f;
        for (int i = q * 128; i < q * 128 + 128; i += 4) {
            float4 kv = *(const float4*)&kt[i];
            p += kv.x * W1[r][i] + kv.y * W1[r][i + 1] + kv.z * W1[r][i + 2] + kv.w * W1[r][i + 3];
        }
        red[q][b][r] = p;
    }
    __syncthreads();
    if (tid < 64) {
        const int b = tid & 31, r = tid >> 5;
        float z = red[0][b][r] + red[1][b][r] + red[2][b][r] + red[3][b][r] + bv1[r];
        hjp[b][r] = z;
        float hh = z * sigm_(z);
        hj[b][r] = hh;
        coh_store(&hG[b * 512 + j0 + r], hh);
    }
    gbar(bar, ++ep);

    for (int t = 0; t < 1024; ++t) {
        const float alpha = scal[t], eta = scal[1024 + t], theta = scal[2048 + t];
        // ======== phase A ========
        float vpre = 0.f;
        if (tid < 64) vpre = Vv[((size_t)t * 32 + (tid & 31)) * 512 + j0 + (tid >> 5)];
        stage_dma<17>(hG, hbuf, tid);               // h(t)  -> A (coherent)
        stage_dma<17>(h2G, buf2, tid);              // h2(t-1) -> B (coherent; garbage at t=0, unused)
        VMCNT0(); __syncthreads();
        {
            const int b = tid & 31, q = (tid >> 5) & 3, half = tid >> 7;
            float p0 = 0.f, p1 = 0.f;
            if (half == 0) {
                for (int j = q * 128; j < q * 128 + 128; j += 4) {
                    float4 hv = *(const float4*)&hbuf[b][j];
                    p0 += hv.x * W2[0][j] + hv.y * W2[0][j + 1] + hv.z * W2[0][j + 2] + hv.w * W2[0][j + 3];
                    p1 += hv.x * W2[1][j] + hv.y * W2[1][j + 1] + hv.z * W2[1][j + 2] + hv.w * W2[1][j + 3];
                }
                red[q][b][0] = p0; red[q][b][1] = p1;
            } else if (t > 0) {
                for (int j = q * 128; j < q * 128 + 128; j += 4) {
                    float4 hv = *(const float4*)&buf2[b][j];
                    p0 += hv.x * W2[0][j] + hv.y * W2[0][j + 1] + hv.z * W2[0][j + 2] + hv.w * W2[0][j + 3];
                    p1 += hv.x * W2[1][j] + hv.y * W2[1][j + 1] + hv.z * W2[1][j + 2] + hv.w * W2[1][j + 3];
                }
                red2[q][b][0] = p0; red2[q][b][1] = p1;
            }
        }
        __syncthreads();
        if (tid < 64) {
            const int b = tid & 31, o = tid >> 5;
            float pred = red[0][b][o] + red[1][b][o] + red[2][b][o] + red[3][b][o] + bv2[o];
            float dp = (pred - vpre) * (2.f / 16384.f);
            dpl[b][o] = dp;
            coh_store(&dpG[b * 512 + j0 + o], dp);
        } else if (tid < 128) {
            if (t > 0) {
                const int b = tid & 31, o = (tid >> 5) & 1;
                float ov = red2[0][b][o] + red2[1][b][o] + red2[2][b][o] + red2[3][b][o] + bv2[o];
                outp[((size_t)(t - 1) * 32 + b) * 512 + j0 + o] = ov;
            }
        }
        __syncthreads();
        if (tid < 2) {
            float db2 = 0.f;
            for (int b = 0; b < 32; ++b) db2 += dpl[b][tid];
            float s = eta * Sb2[tid] - theta * db2;
            Sb2[tid] = s;
            bv2[tid] = (1.f - alpha) * bv2[tid] + s;
        }
        {
            const int j = tid * 2;
            float d00 = 0.f, d01 = 0.f, d10 = 0.f, d11 = 0.f;
            for (int b = 0; b < 32; ++b) {
                float h0 = hbuf[b][j], h1 = hbuf[b][j + 1];
                float q0 = dpl[b][0], q1 = dpl[b][1];
                d00 += q0 * h0; d01 += q0 * h1; d10 += q1 * h0; d11 += q1 * h1;
            }
            float s;
            s = eta * SW2[0][j] - theta * d00;     SW2[0][j] = s;     W2[0][j]     = (1.f - alpha) * W2[0][j] + s;
            s = eta * SW2[0][j + 1] - theta * d01; SW2[0][j + 1] = s; W2[0][j + 1] = (1.f - alpha) * W2[0][j + 1] + s;
            s = eta * SW2[1][j] - theta * d10;     SW2[1][j] = s;     W2[1][j]     = (1.f - alpha) * W2[1][j] + s;
            s = eta * SW2[1][j + 1] - theta * d11; SW2[1][j + 1] = s; W2[1][j + 1] = (1.f - alpha) * W2[1][j + 1] + s;
        }
        gbar(bar, ++ep);

        // ======== phase B (pipelined: K under dh/dW2T, Q under dW1, K2 under GEMM4) ========
        stage_dma<17>(dpG, hbuf, tid);              // dp -> A (coherent)
        stage_dma<0>(Kn + (size_t)t * 16384, buf2, tid);   // K(t) -> B (cached)
        VMCNT16(); __syncthreads();                 // dp(A) ready, K still flying
        {
            const int b = tid & 31, r = (tid >> 5) & 1, q = tid >> 6;
            float p = 0.f;
            for (int o = q * 128; o < q * 128 + 128; o += 4) {
                float4 dv = *(const float4*)&hbuf[b][o];
                p += dv.x * W2T[r][o] + dv.y * W2T[r][o + 1] + dv.z * W2T[r][o + 2] + dv.w * W2T[r][o + 3];
            }
            red[q][b][r] = p;
        }
        __syncthreads();
        if (tid < 64) {
            const int b = tid & 31, r = tid >> 5;
            float dh = red[0][b][r] + red[1][b][r] + red[2][b][r] + red[3][b][r];
            float z = hjp[b][r];
            float sg = sigm_(z);
            dzl[b][r] = dh * (sg * (1.f + z * (1.f - sg)));
        }
        __syncthreads();
        if (tid < 2) {
            float db1 = 0.f;
            for (int b = 0; b < 32; ++b) db1 += dzl[b][tid];
            float s = eta * Sb1[tid] - theta * db1;
            Sb1[tid] = s;
            bv1[tid] = (1.f - alpha) * bv1[tid] + s;
        }
        {
            const int o = tid * 2;
            float d00 = 0.f, d01 = 0.f, d10 = 0.f, d11 = 0.f;
            for (int b = 0; b < 32; ++b) {
                float q0 = hbuf[b][o], q1 = hbuf[b][o + 1];
                float h0 = hj[b][0], h1 = hj[b][1];
                d00 += h0 * q0; d01 += h0 * q1; d10 += h1 * q0; d11 += h1 * q1;
            }
            float s;
            s = eta * SW2T[0][o] - theta * d00;     SW2T[0][o] = s;     W2T[0][o]     = (1.f - alpha) * W2T[0][o] + s;
            s = eta * SW2T[0][o + 1] - theta * d01; SW2T[0][o + 1] = s; W2T[0][o + 1] = (1.f - alpha) * W2T[0][o + 1] + s;
            s = eta * SW2T[1][o] - theta * d10;     SW2T[1][o] = s;     W2T[1][o]     = (1.f - alpha) * W2T[1][o] + s;
            s = eta * SW2T[1][o + 1] - theta * d11; SW2T[1][o + 1] = s; W2T[1][o + 1] = (1.f - alpha) * W2T[1][o + 1] + s;
        }
        __syncthreads();                            // all reads of A done
        stage_dma<0>(Qn + (size_t)t * 16384, hbuf, tid);   // Q(t) -> A (cached)
        VMCNT16(); __syncthreads();                 // K(B) ready, Q still flying
        {
            const int c = tid * 2;
            float d00 = 0.f, d01 = 0.f, d10 = 0.f, d11 = 0.f;
            for (int b = 0; b < 32; ++b) {
                float k0 = buf2[b][c], k1 = buf2[b][c + 1];
                float z0 = dzl[b][0], z1 = dzl[b][1];
                d00 += z0 * k0; d01 += z0 * k1; d10 += z1 * k0; d11 += z1 * k1;
            }
            float s;
            s = eta * SW1[0][c] - theta * d00;     SW1[0][c] = s;     W1[0][c]     = (1.f - alpha) * W1[0][c] + s;
            s = eta * SW1[0][c + 1] - theta * d01; SW1[0][c + 1] = s; W1[0][c + 1] = (1.f - alpha) * W1[0][c + 1] + s;
            s = eta * SW1[1][c] - theta * d10;     SW1[1][c] = s;     W1[1][c]     = (1.f - alpha) * W1[1][c] + s;
            s = eta * SW1[1][c + 1] - theta * d11; SW1[1][c + 1] = s; W1[1][c + 1] = (1.f - alpha) * W1[1][c + 1] + s;
        }
        __syncthreads();                            // all reads of B done
        if (t < 1023) {
            stage_dma<0>(Kn + (size_t)(t + 1) * 16384, buf2, tid);  // K(t+1) -> B
            VMCNT16();                              // Q(A) ready, K2 still flying
        } else {
            VMCNT0();                               // Q(A) ready
        }
        __syncthreads();
        {
            const int b = tid & 31, r = (tid >> 5) & 1, q = tid >> 6;
            float p = 0.f;
            for (int i = q * 128; i < q * 128 + 128; i += 4) {
                float4 qv2 = *(const float4*)&hbuf[b][i];
                p += qv2.x * W1[r][i] + qv2.y * W1[r][i + 1] + qv2.z * W1[r][i + 2] + qv2.w * W1[r][i + 3];
            }
            red[q][b][r] = p;
        }
        __syncthreads();
        VMCNT0(); __syncthreads();                  // K2(B) ready
        if (t < 1023) {
            const int b = tid & 31, r = (tid >> 5) & 1, q = tid >> 6;
            float p = 0.f;
            for (int i = q * 128; i < q * 128 + 128; i += 4) {
                float4 kv2 = *(const float4*)&buf2[b][i];
                p += kv2.x * W1[r][i] + kv2.y * W1[r][i + 1] + kv2.z * W1[r][i + 2] + kv2.w * W1[r][i + 3];
            }
            red2[q][b][r] = p;
        }
        __syncthreads();
        if (tid < 64) {
            const int b = tid & 31, r = tid >> 5;
            float z2 = red[0][b][r] + red[1][b][r] + red[2][b][r] + red[3][b][r] + bv1[r];
            coh_store(&h2G[b * 512 + j0 + r], z2 * sigm_(z2));
            if (t < 1023) {
                float z = red2[0][b][r] + red2[1][b][r] + red2[2][b][r] + red2[3][b][r] + bv1[r];
                hjp[b][r] = z;
                float hh = z * sigm_(z);
                hj[b][r] = hh;
                coh_store(&hG[b * 512 + j0 + r], hh);
            }
        }
        gbar(bar, ++ep);
    }

    // ---- epilogue: out[1023] = h2(1023) @ W2(1023).T + b2(1023) ----
    stage_dma<17>(h2G, hbuf, tid);
    VMCNT0(); __syncthreads();
    {
        const int b = tid & 31, q = (tid >> 5) & 3, half = tid >> 7;
        if (half == 0) {
            float p0 = 0.f, p1 = 0.f;
            for (int j = q * 128; j < q * 128 + 128; j += 4) {
                float4 hv = *(const float4*)&hbuf[b][j];
                p0 += hv.x * W2[0][j] + hv.y * W2[0][j + 1] + hv.z * W2[0][j + 2] + hv.w * W2[0][j + 3];
                p1 += hv.x * W2[1][j] + hv.y * W2[1][j + 1] + hv.z * W2[1][j + 2] + hv.w * W2[1][j + 3];
            }
            red[q][b][0] = p0; red[q][b][1] = p1;
        }
        __syncthreads();
        if (tid < 64) {
            const int b = tid & 31, o = tid >> 5;
            float ov = red[0][b][o] + red[1][b][o] + red[2][b][o] + red[3][b][o] + bv2[o];
            outp[((size_t)1023 * 32 + b) * 512 + j0 + o] = ov;
        }
    }
}

extern "C" void kernel_launch(void* const* d_in, const int* in_sizes, int n_in,
                              void* d_out, int out_size, void* d_ws, size_t ws_size,
                              hipStream_t stream) {
    (void)in_sizes; (void)n_in; (void)out_size; (void)ws_size;
    const float* x    = (const float*)d_in[0];
    const float* Wk_w = (const float*)d_in[1];
    const float* Wk_b = (const float*)d_in[2];
    const float* Wv_w = (const float*)d_in[3];
    const float* Wv_b = (const float*)d_in[4];
    const float* Wq_w = (const float*)d_in[5];
    const float* Wq_b = (const float*)d_in[6];
    const float* ck_w = (const float*)d_in[7];
    const float* ck_b = (const float*)d_in[8];
    const float* cv_w = (const float*)d_in[9];
    const float* cv_b = (const float*)d_in[10];
    const float* cq_w = (const float*)d_in[11];
    const float* cq_b = (const float*)d_in[12];
    const float* MW1  = (const float*)d_in[13];
    const float* Mb1  = (const float*)d_in[14];
    const float* MW2  = (const float*)d_in[15];
    const float* Mb2  = (const float*)d_in[16];
    const float* a_w  = (const float*)d_in[17];
    const float* a_b  = (const float*)d_in[18];
    const float* e_w  = (const float*)d_in[19];
    const float* e_b  = (const float*)d_in[20];
    const float* t_w  = (const float*)d_in[21];
    const float* t_b  = (const float*)d_in[22];

    float* out = (float*)d_out;
    float* ws = (float*)d_ws;
    float* Kb   = ws;                    // [1024][32][512]
    float* Vb   = Kb + 16777216;
    float* Qb   = Vb + 16777216;
    float* scal = Qb + 16777216;         // [3][1024]
    float* hG   = scal + 3072;           // [32][512]
    float* dpG  = hG + 16384;
    float* h2G  = dpG + 16384;
    unsigned* bar = (unsigned*)(h2G + 16384);  // arr[256] arrivals + flag@320; memset 8KB
    float* tmp  = out;                   // reuse d_out as pre-conv scratch

    hipMemsetAsync(bar, 0, 8192, stream);
    scalars_kernel<<<1024, 256, 0, stream>>>(x, a_w, a_b, e_w, e_b, t_w, t_b, scal);
    proj_gemm<<<dim3(512, 8), 256, 0, stream>>>(x, Wk_w, Wk_b, tmp);
    conv_kernel<<<16384, 256, 0, stream>>>(tmp, ck_w, ck_b, Kb);
    proj_gemm<<<dim3(512, 8), 256, 0, stream>>>(x, Wv_w, Wv_b, tmp);
    conv_kernel<<<16384, 256, 0, stream>>>(tmp, cv_w, cv_b, Vb);
    proj_gemm<<<dim3(512, 8), 256, 0, stream>>>(x, Wq_w, Wq_b, tmp);
    conv_kernel<<<16384, 256, 0, stream>>>(tmp, cq_w, cq_b, Qb);
    l2norm_kernel<<<16384, 256, 0, stream>>>(Kb, Qb);

    const float *aKn = Kb, *aV = Vb, *aQn = Qb, *aSc = scal;
    const float *aW1 = MW1, *ab1 = Mb1, *aW2 = MW2, *ab2 = Mb2;
    float *ahG = hG, *adpG = dpG, *ah2G = h2G, *aout = out;
    unsigned* abar = bar;
    void* kargs[] = {(void*)&aKn, (void*)&aV, (void*)&aQn, (void*)&aSc,
                     (void*)&aW1, (void*)&ab1, (void*)&aW2, (void*)&ab2,
                     (void*)&ahG, (void*)&adpG, (void*)&ah2G, (void*)&aout, (void*)&abar};
    hipError_t ce = hipLaunchCooperativeKernel((void*)scan_kernel, dim3(NBLK), dim3(NTHR), kargs, 0, stream);
    if (ce != hipSuccess) {
        // Cooperative validation rejected the kernel; our barrier only needs co-residency
        // (grid == 256 CUs, 160KB LDS forces 1 block/CU), so fall back to a regular launch.
        scan_kernel<<<dim3(NBLK), dim3(NTHR), 0, stream>>>(
            Kb, Vb, Qb, scal, MW1, Mb1, MW2, Mb2, hG, dpG, h2G, out, bar);
    }
}

// Round 13
// 14836.174 us; speedup vs baseline: 1.4316x; 1.0668x over previous
//
#include <hip/hip_runtime.h>

#define NTHR 512
#define NBLK 256   // one block per 2 rows of the 512-wide hidden dims

#define GLOBAL_AS __attribute__((address_space(1)))
#define LDS_AS    __attribute__((address_space(3)))

#define VMCNT0() asm volatile("s_waitcnt vmcnt(0)" ::: "memory")
#define VMCNT8() asm volatile("s_waitcnt vmcnt(8)" ::: "memory")

__device__ __forceinline__ float sigm_(float z) { return 1.f / (1.f + expf(-z)); }

__device__ __forceinline__ void coh_store(float* p, float v) {
    __hip_atomic_store(p, v, __ATOMIC_RELAXED, __HIP_MEMORY_SCOPE_AGENT);
}
__device__ __forceinline__ unsigned coh_loadu(const unsigned* p) {
    return __hip_atomic_load(p, __ATOMIC_RELAXED, __HIP_MEMORY_SCOPE_AGENT);
}

// ---- split barrier: flat arrival stores + single-poller detection (round-12 form).
// arrive() after the producer stores; local-only work can run between arrive and wait,
// hidden under the ~2.5us cross-XCD propagation.
__device__ __forceinline__ void gbar_arrive(unsigned* arr, unsigned ep) {
    if (threadIdx.x == 0) {
        asm volatile("s_waitcnt vmcnt(0)" ::: "memory");   // wave-0 coh stores visible at IC
        __hip_atomic_store(arr + blockIdx.x, ep, __ATOMIC_RELAXED, __HIP_MEMORY_SCOPE_AGENT);
    }
}
__device__ __forceinline__ void gbar_wait(unsigned* arr, unsigned ep) {
    if (blockIdx.x == 0) {
        if (threadIdx.x < 64) {
            const unsigned* a4 = arr + threadIdx.x * 4;
            for (;;) {
                unsigned m0 = coh_loadu(a4 + 0);
                unsigned m1 = coh_loadu(a4 + 1);
                unsigned m2 = coh_loadu(a4 + 2);
                unsigned m3 = coh_loadu(a4 + 3);
                bool ok = (m0 >= ep) & (m1 >= ep) & (m2 >= ep) & (m3 >= ep);
                if (__all(ok)) break;
                __builtin_amdgcn_s_sleep(1);
            }
            if (threadIdx.x == 0)
                __hip_atomic_store(arr + 320, ep, __ATOMIC_RELAXED, __HIP_MEMORY_SCOPE_AGENT);
        }
    } else if (threadIdx.x == 0) {
        while (coh_loadu(arr + 320) < ep) __builtin_amdgcn_s_sleep(1);
    }
    __syncthreads();
}

// ---- async DMA staging (512 threads: 8 waves x 8 DMAs). AUX=17 coherent, AUX=0 cached.
template <int AUX>
__device__ __forceinline__ void stage_dma(const float* __restrict__ src, float (*hb)[516], int tid) {
    const int lane = tid & 63;
    const int wbase = tid - lane;                 // 0..448
#pragma unroll
    for (int l = 0; l < 8; ++l) {
        const int e0 = wbase + l * 512;           // wave's first float4 index this iter
        const float* g = src + (size_t)(e0 + lane) * 4;
        float* d = &hb[e0 >> 7][(e0 & 127) << 2];
        __builtin_amdgcn_global_load_lds((const GLOBAL_AS unsigned int*)g,
                                         (LDS_AS unsigned int*)d, 16, 0, AUX);
    }
}

// ---------------- projection GEMM ----------------
__global__ void proj_gemm(const float* __restrict__ A, const float* __restrict__ W,
                          const float* __restrict__ bias, float* __restrict__ C) {
    __shared__ float As[64][33];
    __shared__ float Ws[64][33];
    const int bn = blockIdx.x * 64, bc = blockIdx.y * 64;
    const int tx = threadIdx.x & 15, ty = threadIdx.x >> 4;
    float acc[4][4] = {};
    for (int k0 = 0; k0 < 512; k0 += 32) {
#pragma unroll
        for (int l = 0; l < 2; ++l) {
            int f4 = threadIdx.x + l * 256;
            int row = f4 >> 3;
            int kk = (f4 & 7) << 2;
            float4 av = *(const float4*)&A[(size_t)(bn + row) * 512 + k0 + kk];
            float4 wv = *(const float4*)&W[(size_t)(bc + row) * 512 + k0 + kk];
            As[row][kk] = av.x; As[row][kk + 1] = av.y; As[row][kk + 2] = av.z; As[row][kk + 3] = av.w;
            Ws[row][kk] = wv.x; Ws[row][kk + 1] = wv.y; Ws[row][kk + 2] = wv.z; Ws[row][kk + 3] = wv.w;
        }
        __syncthreads();
#pragma unroll
        for (int kk = 0; kk < 32; ++kk) {
            float a0 = As[ty * 4 + 0][kk], a1 = As[ty * 4 + 1][kk], a2 = As[ty * 4 + 2][kk], a3 = As[ty * 4 + 3][kk];
            float w0 = Ws[tx * 4 + 0][kk], w1 = Ws[tx * 4 + 1][kk], w2 = Ws[tx * 4 + 2][kk], w3 = Ws[tx * 4 + 3][kk];
            acc[0][0] += a0 * w0; acc[0][1] += a0 * w1; acc[0][2] += a0 * w2; acc[0][3] += a0 * w3;
            acc[1][0] += a1 * w0; acc[1][1] += a1 * w1; acc[1][2] += a1 * w2; acc[1][3] += a1 * w3;
            acc[2][0] += a2 * w0; acc[2][1] += a2 * w1; acc[2][2] += a2 * w2; acc[2][3] += a2 * w3;
            acc[3][0] += a3 * w0; acc[3][1] += a3 * w1; acc[3][2] += a3 * w2; acc[3][3] += a3 * w3;
        }
        __syncthreads();
    }
    float4 bvv = *(const float4*)&bias[bc + tx * 4];
#pragma unroll
    for (int i = 0; i < 4; ++i) {
        float4 o = make_float4(acc[i][0] + bvv.x, acc[i][1] + bvv.y, acc[i][2] + bvv.z, acc[i][3] + bvv.w);
        *(float4*)&C[(size_t)(bn + ty * 4 + i) * 512 + bc + tx * 4] = o;
    }
}

// ---------------- depthwise conv ----------------
__global__ void conv_kernel(const float* __restrict__ P, const float* __restrict__ cw,
                            const float* __restrict__ cb, float* __restrict__ O) {
    int idx = blockIdx.x * 256 + threadIdx.x;
    if (idx >= 1024 * 32 * 128) return;
    int c4 = (idx & 127) << 2;
    int sb = idx >> 7;
    int s = sb >> 5, b = sb & 31;
    float acc0 = cb[c4 + 0], acc1 = cb[c4 + 1], acc2 = cb[c4 + 2], acc3 = cb[c4 + 3];
#pragma unroll
    for (int d = 0; d < 3; ++d) {
        int s2 = s + d - 1;
        if (s2 < 0 || s2 >= 1024) continue;
        float4 pv = *(const float4*)&P[((size_t)s2 * 32 + b) * 512 + c4];
        acc0 += pv.x * cw[(c4 + 0) * 3 + d];
        acc1 += pv.y * cw[(c4 + 1) * 3 + d];
        acc2 += pv.z * cw[(c4 + 2) * 3 + d];
        acc3 += pv.w * cw[(c4 + 3) * 3 + d];
    }
    *(float4*)&O[(size_t)sb * 512 + c4] = make_float4(acc0, acc1, acc2, acc3);
}

// ---------------- per-step scalars ----------------
__global__ void scalars_kernel(const float* __restrict__ x,
                               const float* __restrict__ aw, const float* __restrict__ ab,
                               const float* __restrict__ ew, const float* __restrict__ eb,
                               const float* __restrict__ tw, const float* __restrict__ tb,
                               float* __restrict__ scal) {
    const int t = blockIdx.x, tid = threadIdx.x;
    const int b = tid >> 3, part = tid & 7;
    const float* xp = x + ((size_t)t * 32 + b) * 512 + part * 64;
    float sa = 0.f, se = 0.f, st = 0.f;
    for (int i = 0; i < 64; i += 4) {
        float4 xv = *(const float4*)&xp[i];
        float4 av = *(const float4*)&aw[part * 64 + i];
        float4 ev = *(const float4*)&ew[part * 64 + i];
        float4 tv = *(const float4*)&tw[part * 64 + i];
        sa += xv.x * av.x + xv.y * av.y + xv.z * av.z + xv.w * av.w;
        se += xv.x * ev.x + xv.y * ev.y + xv.z * ev.z + xv.w * ev.w;
        st += xv.x * tv.x + xv.y * tv.y + xv.z * tv.z + xv.w * tv.w;
    }
#pragma unroll
    for (int m = 1; m < 8; m <<= 1) {
        sa += __shfl_xor(sa, m);
        se += __shfl_xor(se, m);
        st += __shfl_xor(st, m);
    }
    __shared__ float ra[32], re[32], rt[32];
    if (part == 0) {
        ra[b] = sigm_(sa + ab[0]);
        re[b] = sigm_(se + eb[0]);
        float z = st + tb[0];
        rt[b] = fmaxf(z, 0.f) + log1pf(expf(-fabsf(z)));
    }
    __syncthreads();
    if (tid == 0) { float s = 0.f; for (int i = 0; i < 32; ++i) s += ra[i]; scal[t] = s / 32.f; }
    if (tid == 1) { float s = 0.f; for (int i = 0; i < 32; ++i) s += re[i]; scal[1024 + t] = s / 32.f; }
    if (tid == 2) { float s = 0.f; for (int i = 0; i < 32; ++i) s += rt[i]; scal[2048 + t] = s / 32.f; }
}

// ---------------- l2-normalize K,Q ----------------
__global__ void l2norm_kernel(float* __restrict__ Kb, float* __restrict__ Qb) {
    int w = (blockIdx.x * 256 + threadIdx.x) >> 6;
    int lane = threadIdx.x & 63;
    if (w >= 2 * 32768) return;
    float* row = (w < 32768) ? (Kb + (size_t)w * 512) : (Qb + (size_t)(w - 32768) * 512);
    float4 v0 = *(float4*)&row[lane * 8];
    float4 v1 = *(float4*)&row[lane * 8 + 4];
    float ss = v0.x * v0.x + v0.y * v0.y + v0.z * v0.z + v0.w * v0.w
             + v1.x * v1.x + v1.y * v1.y + v1.z * v1.z + v1.w * v1.w;
#pragma unroll
    for (int m = 1; m < 64; m <<= 1) ss += __shfl_xor(ss, m);
    float inv = 1.f / fmaxf(sqrtf(ss), 1e-12f);
    v0.x *= inv; v0.y *= inv; v0.z *= inv; v0.w *= inv;
    v1.x *= inv; v1.y *= inv; v1.z *= inv; v1.w *= inv;
    *(float4*)&row[lane * 8] = v0;
    *(float4*)&row[lane * 8 + 4] = v1;
}

// ---------------- TTT scan: 512 threads, dbuf coherent DMA, split barrier ----------------
__global__ void __launch_bounds__(NTHR, 1) scan_kernel(
    const float* __restrict__ Kn, const float* __restrict__ Vv, const float* __restrict__ Qn,
    const float* __restrict__ scal,
    const float* __restrict__ MW1_0, const float* __restrict__ Mb1_0,
    const float* __restrict__ MW2_0, const float* __restrict__ Mb2_0,
    float* __restrict__ hG, float* __restrict__ dpG, float* __restrict__ h2G,
    float* __restrict__ outp, unsigned* __restrict__ bar) {
    const int g = blockIdx.x;
    const int tid = threadIdx.x;
    const int j0 = g * 2;
    unsigned ep = 0;

    __shared__ float W1[2][512], SW1[2][512];
    __shared__ float W2[2][512], SW2[2][512];
    __shared__ float W2T[2][512], SW2T[2][512];
    __shared__ float hbuf[32][516];                 // buffer A
    __shared__ float buf2[32][516];                 // buffer B
    __shared__ float red[8][32][2], red2[8][32][2];
    __shared__ float dpl[32][2], dzl[32][2], hj[32][2], hjp[32][2];
    __shared__ float bv1[2], Sb1[2], bv2[2], Sb2[2];

    for (int c = tid; c < 512; c += NTHR) {
#pragma unroll
        for (int r = 0; r < 2; ++r) {
            W1[r][c] = MW1_0[(size_t)(j0 + r) * 512 + c];
            W2[r][c] = MW2_0[(size_t)(j0 + r) * 512 + c];
            W2T[r][c] = MW2_0[(size_t)c * 512 + (j0 + r)];
            SW1[r][c] = 0.f; SW2[r][c] = 0.f; SW2T[r][c] = 0.f;
        }
    }
    if (tid < 2) { bv1[tid] = Mb1_0[j0 + tid]; Sb1[tid] = 0.f; bv2[tid] = Mb2_0[j0 + tid]; Sb2[tid] = 0.f; }
    __syncthreads();
    // h(0) = silu(ktn(0) @ W1.T + b1)
    {
        const int b = tid & 31, r = (tid >> 5) & 1, q = tid >> 6;   // q 0..7
        const float* kt = Kn + (size_t)b * 512;
        float p = 0.f;
        for (int i = q * 64; i < q * 64 + 64; i += 4) {
            float4 kv = *(const float4*)&kt[i];
            p += kv.x * W1[r][i] + kv.y * W1[r][i + 1] + kv.z * W1[r][i + 2] + kv.w * W1[r][i + 3];
        }
        red[q][b][r] = p;
    }
    __syncthreads();
    if (tid < 64) {
        const int b = tid & 31, r = tid >> 5;
        float z = bv1[r];
#pragma unroll
        for (int q = 0; q < 8; ++q) z += red[q][b][r];
        hjp[b][r] = z;
        float hh = z * sigm_(z);
        hj[b][r] = hh;
        coh_store(&hG[b * 512 + j0 + r], hh);
    }
    __syncthreads();
    ++ep; gbar_arrive(bar, ep); gbar_wait(bar, ep);

    for (int t = 0; t < 1024; ++t) {
        const float alpha = scal[t], eta = scal[1024 + t], theta = scal[2048 + t];
        // ======== phase A ========
        float vpre = 0.f;
        if (tid < 64) vpre = Vv[((size_t)t * 32 + (tid & 31)) * 512 + j0 + (tid >> 5)];
        stage_dma<17>(hG, hbuf, tid);               // h(t)  -> A (coherent)
        stage_dma<17>(h2G, buf2, tid);              // h2(t-1) -> B
        VMCNT0(); __syncthreads();
        {
            const int b = tid & 31, q = (tid >> 5) & 7;
            float p0 = 0.f, p1 = 0.f;
            if (tid < 256) {                        // pred partials from A
                for (int j = q * 64; j < q * 64 + 64; j += 4) {
                    float4 hv = *(const float4*)&hbuf[b][j];
                    p0 += hv.x * W2[0][j] + hv.y * W2[0][j + 1] + hv.z * W2[0][j + 2] + hv.w * W2[0][j + 3];
                    p1 += hv.x * W2[1][j] + hv.y * W2[1][j + 1] + hv.z * W2[1][j + 2] + hv.w * W2[1][j + 3];
                }
                red[q][b][0] = p0; red[q][b][1] = p1;
            } else if (t > 0) {                     // out[t-1] partials from B
                for (int j = q * 64; j < q * 64 + 64; j += 4) {
                    float4 hv = *(const float4*)&buf2[b][j];
                    p0 += hv.x * W2[0][j] + hv.y * W2[0][j + 1] + hv.z * W2[0][j + 2] + hv.w * W2[0][j + 3];
                    p1 += hv.x * W2[1][j] + hv.y * W2[1][j + 1] + hv.z * W2[1][j + 2] + hv.w * W2[1][j + 3];
                }
                red2[q][b][0] = p0; red2[q][b][1] = p1;
            }
        }
        __syncthreads();
        if (tid < 64) {
            const int b = tid & 31, o = tid >> 5;
            float pred = bv2[o];
#pragma unroll
            for (int q = 0; q < 8; ++q) pred += red[q][b][o];
            float dp = (pred - vpre) * (2.f / 16384.f);
            dpl[b][o] = dp;
            coh_store(&dpG[b * 512 + j0 + o], dp);
        } else if (tid < 128) {
            if (t > 0) {
                const int b = tid & 31, o = (tid >> 5) & 1;
                float ov = bv2[o];
#pragma unroll
                for (int q = 0; q < 8; ++q) ov += red2[q][b][o];
                outp[((size_t)(t - 1) * 32 + b) * 512 + j0 + o] = ov;
            }
        }
        __syncthreads();
        ++ep; gbar_arrive(bar, ep);                 // dp published; hide local updates below
        if (tid < 2) {                              // b2 update
            float db2 = 0.f;
            for (int b = 0; b < 32; ++b) db2 += dpl[b][tid];
            float s = eta * Sb2[tid] - theta * db2;
            Sb2[tid] = s;
            bv2[tid] = (1.f - alpha) * bv2[tid] + s;
        }
        {                                           // dW2 update (1 col/thread)
            const int j = tid;
            float d00 = 0.f, d10 = 0.f;
            for (int b = 0; b < 32; ++b) {
                float h0 = hbuf[b][j];
                d00 += dpl[b][0] * h0;
                d10 += dpl[b][1] * h0;
            }
            float s;
            s = eta * SW2[0][j] - theta * d00; SW2[0][j] = s; W2[0][j] = (1.f - alpha) * W2[0][j] + s;
            s = eta * SW2[1][j] - theta * d10; SW2[1][j] = s; W2[1][j] = (1.f - alpha) * W2[1][j] + s;
        }
        gbar_wait(bar, ep);

        // ======== phase B ========
        stage_dma<17>(dpG, hbuf, tid);              // dp -> A (coherent)
        stage_dma<0>(Kn + (size_t)t * 16384, buf2, tid);   // K(t) -> B
        VMCNT8(); __syncthreads();                  // dp ready, K flying
        {
            const int b = tid & 31, r = (tid >> 5) & 1, q = tid >> 6;
            float p = 0.f;
            for (int o = q * 64; o < q * 64 + 64; o += 4) {
                float4 dv = *(const float4*)&hbuf[b][o];
                p += dv.x * W2T[r][o] + dv.y * W2T[r][o + 1] + dv.z * W2T[r][o + 2] + dv.w * W2T[r][o + 3];
            }
            red[q][b][r] = p;
        }
        __syncthreads();
        if (tid < 64) {
            const int b = tid & 31, r = tid >> 5;
            float dh = 0.f;
#pragma unroll
            for (int q = 0; q < 8; ++q) dh += red[q][b][r];
            float z = hjp[b][r];
            float sg = sigm_(z);
            dzl[b][r] = dh * (sg * (1.f + z * (1.f - sg)));
        }
        __syncthreads();
        if (tid < 2) {                              // b1 update
            float db1 = 0.f;
            for (int b = 0; b < 32; ++b) db1 += dzl[b][tid];
            float s = eta * Sb1[tid] - theta * db1;
            Sb1[tid] = s;
            bv1[tid] = (1.f - alpha) * bv1[tid] + s;
        }
        {                                           // dW2T update (1 col/thread)
            const int o = tid;
            float d00 = 0.f, d10 = 0.f;
            for (int b = 0; b < 32; ++b) {
                float q0 = hbuf[b][o];
                d00 += hj[b][0] * q0;
                d10 += hj[b][1] * q0;
            }
            float s;
            s = eta * SW2T[0][o] - theta * d00; SW2T[0][o] = s; W2T[0][o] = (1.f - alpha) * W2T[0][o] + s;
            s = eta * SW2T[1][o] - theta * d10; SW2T[1][o] = s; W2T[1][o] = (1.f - alpha) * W2T[1][o] + s;
        }
        __syncthreads();                            // A reads done
        stage_dma<0>(Qn + (size_t)t * 16384, hbuf, tid);   // Q(t) -> A
        VMCNT8(); __syncthreads();                  // K ready, Q flying
        {                                           // dW1 update (1 col/thread)
            const int c = tid;
            float d00 = 0.f, d10 = 0.f;
            for (int b = 0; b < 32; ++b) {
                float k0 = buf2[b][c];
                d00 += dzl[b][0] * k0;
                d10 += dzl[b][1] * k0;
            }
            float s;
            s = eta * SW1[0][c] - theta * d00; SW1[0][c] = s; W1[0][c] = (1.f - alpha) * W1[0][c] + s;
            s = eta * SW1[1][c] - theta * d10; SW1[1][c] = s; W1[1][c] = (1.f - alpha) * W1[1][c] + s;
        }
        __syncthreads();                            // B reads done
        if (t < 1023) {
            stage_dma<0>(Kn + (size_t)(t + 1) * 16384, buf2, tid);  // K(t+1) -> B
            VMCNT8();                               // Q ready, K2 flying
        } else {
            VMCNT0();
        }
        __syncthreads();
        {                                           // GEMM4: h2 partials from Q(A)
            const int b = tid & 31, r = (tid >> 5) & 1, q = tid >> 6;
            float p = 0.f;
            for (int i = q * 64; i < q * 64 + 64; i += 4) {
                float4 qv2 = *(const float4*)&hbuf[b][i];
                p += qv2.x * W1[r][i] + qv2.y * W1[r][i + 1] + qv2.z * W1[r][i + 2] + qv2.w * W1[r][i + 3];
            }
            red[q][b][r] = p;
        }
        __syncthreads();
        VMCNT0(); __syncthreads();                  // K2 ready
        if (t < 1023) {                             // GEMM1: h(t+1) partials from K2(B)
            const int b = tid & 31, r = (tid >> 5) & 1, q = tid >> 6;
            float p = 0.f;
            for (int i = q * 64; i < q * 64 + 64; i += 4) {
                float4 kv2 = *(const float4*)&buf2[b][i];
                p += kv2.x * W1[r][i] + kv2.y * W1[r][i + 1] + kv2.z * W1[r][i + 2] + kv2.w * W1[r][i + 3];
            }
            red2[q][b][r] = p;
        }
        __syncthreads();
        if (tid < 64) {
            const int b = tid & 31, r = tid >> 5;
            float z2 = bv1[r];
#pragma unroll
            for (int q = 0; q < 8; ++q) z2 += red[q][b][r];
            coh_store(&h2G[b * 512 + j0 + r], z2 * sigm_(z2));
            if (t < 1023) {
                float z = bv1[r];
#pragma unroll
                for (int q = 0; q < 8; ++q) z += red2[q][b][r];
                hjp[b][r] = z;
                float hh = z * sigm_(z);
                hj[b][r] = hh;
                coh_store(&hG[b * 512 + j0 + r], hh);
            }
        }
        __syncthreads();
        ++ep; gbar_arrive(bar, ep); gbar_wait(bar, ep);
    }

    // ---- epilogue: out[1023] = h2(1023) @ W2(1023).T + b2(1023) ----
    stage_dma<17>(h2G, hbuf, tid);
    VMCNT0(); __syncthreads();
    if (tid < 256) {
        const int b = tid & 31, q = (tid >> 5) & 7;
        float p0 = 0.f, p1 = 0.f;
        for (int j = q * 64; j < q * 64 + 64; j += 4) {
            float4 hv = *(const float4*)&hbuf[b][j];
            p0 += hv.x * W2[0][j] + hv.y * W2[0][j + 1] + hv.z * W2[0][j + 2] + hv.w * W2[0][j + 3];
            p1 += hv.x * W2[1][j] + hv.y * W2[1][j + 1] + hv.z * W2[1][j + 2] + hv.w * W2[1][j + 3];
        }
        red[q][b][0] = p0; red[q][b][1] = p1;
    }
    __syncthreads();
    if (tid < 64) {
        const int b = tid & 31, o = tid >> 5;
        float ov = bv2[o];
#pragma unroll
        for (int q = 0; q < 8; ++q) ov += red[q][b][o];
        outp[((size_t)1023 * 32 + b) * 512 + j0 + o] = ov;
    }
}

extern "C" void kernel_launch(void* const* d_in, const int* in_sizes, int n_in,
                              void* d_out, int out_size, void* d_ws, size_t ws_size,
                              hipStream_t stream) {
    (void)in_sizes; (void)n_in; (void)out_size; (void)ws_size;
    const float* x    = (const float*)d_in[0];
    const float* Wk_w = (const float*)d_in[1];
    const float* Wk_b = (const float*)d_in[2];
    const float* Wv_w = (const float*)d_in[3];
    const float* Wv_b = (const float*)d_in[4];
    const float* Wq_w = (const float*)d_in[5];
    const float* Wq_b = (const float*)d_in[6];
    const float* ck_w = (const float*)d_in[7];
    const float* ck_b = (const float*)d_in[8];
    const float* cv_w = (const float*)d_in[9];
    const float* cv_b = (const float*)d_in[10];
    const float* cq_w = (const float*)d_in[11];
    const float* cq_b = (const float*)d_in[12];
    const float* MW1  = (const float*)d_in[13];
    const float* Mb1  = (const float*)d_in[14];
    const float* MW2  = (const float*)d_in[15];
    const float* Mb2  = (const float*)d_in[16];
    const float* a_w  = (const float*)d_in[17];
    const float* a_b  = (const float*)d_in[18];
    const float* e_w  = (const float*)d_in[19];
    const float* e_b  = (const float*)d_in[20];
    const float* t_w  = (const float*)d_in[21];
    const float* t_b  = (const float*)d_in[22];

    float* out = (float*)d_out;
    float* ws = (float*)d_ws;
    float* Kb   = ws;                    // [1024][32][512]
    float* Vb   = Kb + 16777216;
    float* Qb   = Vb + 16777216;
    float* scal = Qb + 16777216;         // [3][1024]
    float* hG   = scal + 3072;           // [32][512]
    float* dpG  = hG + 16384;
    float* h2G  = dpG + 16384;
    unsigned* bar = (unsigned*)(h2G + 16384);  // arr[256] + flag@320; memset 8KB
    float* tmp  = out;                   // reuse d_out as pre-conv scratch

    hipMemsetAsync(bar, 0, 8192, stream);
    scalars_kernel<<<1024, 256, 0, stream>>>(x, a_w, a_b, e_w, e_b, t_w, t_b, scal);
    proj_gemm<<<dim3(512, 8), 256, 0, stream>>>(x, Wk_w, Wk_b, tmp);
    conv_kernel<<<16384, 256, 0, stream>>>(tmp, ck_w, ck_b, Kb);
    proj_gemm<<<dim3(512, 8), 256, 0, stream>>>(x, Wv_w, Wv_b, tmp);
    conv_kernel<<<16384, 256, 0, stream>>>(tmp, cv_w, cv_b, Vb);
    proj_gemm<<<dim3(512, 8), 256, 0, stream>>>(x, Wq_w, Wq_b, tmp);
    conv_kernel<<<16384, 256, 0, stream>>>(tmp, cq_w, cq_b, Qb);
    l2norm_kernel<<<16384, 256, 0, stream>>>(Kb, Qb);

    const float *aKn = Kb, *aV = Vb, *aQn = Qb, *aSc = scal;
    const float *aW1 = MW1, *ab1 = Mb1, *aW2 = MW2, *ab2 = Mb2;
    float *ahG = hG, *adpG = dpG, *ah2G = h2G, *aout = out;
    unsigned* abar = bar;
    void* kargs[] = {(void*)&aKn, (void*)&aV, (void*)&aQn, (void*)&aSc,
                     (void*)&aW1, (void*)&ab1, (void*)&aW2, (void*)&ab2,
                     (void*)&ahG, (void*)&adpG, (void*)&ah2G, (void*)&aout, (void*)&abar};
    hipError_t ce = hipLaunchCooperativeKernel((void*)scan_kernel, dim3(NBLK), dim3(NTHR), kargs, 0, stream);
    if (ce != hipSuccess) {
        // Cooperative validation rejected the kernel; our barrier only needs co-residency
        // (grid == 256 CUs, ~158KB LDS forces 1 block/CU), so fall back to a regular launch.
        scan_kernel<<<dim3(NBLK), dim3(NTHR), 0, stream>>>(
            Kb, Vb, Qb, scal, MW1, Mb1, MW2, Mb2, hG, dpG, h2G, out, bar);
    }
}

// Round 14
// 14178.221 us; speedup vs baseline: 1.4981x; 1.0464x over previous
//
#include <hip/hip_runtime.h>

#define NTHR 512
#define NBLK 256   // one block per 2 rows of the 512-wide hidden dims

#define GLOBAL_AS __attribute__((address_space(1)))
#define LDS_AS    __attribute__((address_space(3)))

#define VMCNT0() asm volatile("s_waitcnt vmcnt(0)" ::: "memory")
#define VMCNT8() asm volatile("s_waitcnt vmcnt(8)" ::: "memory")

__device__ __forceinline__ float sigm_(float z) { return 1.f / (1.f + expf(-z)); }

__device__ __forceinline__ void coh_store(float* p, float v) {
    __hip_atomic_store(p, v, __ATOMIC_RELAXED, __HIP_MEMORY_SCOPE_AGENT);
}
__device__ __forceinline__ unsigned coh_loadu(const unsigned* p) {
    return __hip_atomic_load(p, __ATOMIC_RELAXED, __HIP_MEMORY_SCOPE_AGENT);
}

// ---- split barrier: flat arrival stores + single-poller detection + flag broadcast.
// Local work (and prefetch DMA issue) runs between arrive and wait, hidden under
// the ~2.5us cross-XCD propagation. Tight spins (no s_sleep): 1 poller block and
// 255 single-thread flag readers — read-sharing one line is benign (rounds 2-4).
__device__ __forceinline__ void gbar_arrive(unsigned* arr, unsigned ep) {
    if (threadIdx.x == 0) {
        asm volatile("s_waitcnt vmcnt(0)" ::: "memory");   // wave-0 coh stores visible at IC
        __hip_atomic_store(arr + blockIdx.x, ep, __ATOMIC_RELAXED, __HIP_MEMORY_SCOPE_AGENT);
    }
}
__device__ __forceinline__ void gbar_wait(unsigned* arr, unsigned ep) {
    if (blockIdx.x == 0) {
        if (threadIdx.x < 64) {
            const unsigned* a4 = arr + threadIdx.x * 4;
            for (;;) {
                unsigned m0 = coh_loadu(a4 + 0);
                unsigned m1 = coh_loadu(a4 + 1);
                unsigned m2 = coh_loadu(a4 + 2);
                unsigned m3 = coh_loadu(a4 + 3);
                bool ok = (m0 >= ep) & (m1 >= ep) & (m2 >= ep) & (m3 >= ep);
                if (__all(ok)) break;
            }
            if (threadIdx.x == 0)
                __hip_atomic_store(arr + 320, ep, __ATOMIC_RELAXED, __HIP_MEMORY_SCOPE_AGENT);
        }
    } else if (threadIdx.x == 0) {
        while (coh_loadu(arr + 320) < ep) {}
    }
    __syncthreads();
}

// ---- async DMA staging (512 threads: 8 waves x 8 DMAs). AUX=17 coherent, AUX=0 cached.
template <int AUX>
__device__ __forceinline__ void stage_dma(const float* __restrict__ src, float (*hb)[516], int tid) {
    const int lane = tid & 63;
    const int wbase = tid - lane;                 // 0..448
#pragma unroll
    for (int l = 0; l < 8; ++l) {
        const int e0 = wbase + l * 512;
        const float* g = src + (size_t)(e0 + lane) * 4;
        float* d = &hb[e0 >> 7][(e0 & 127) << 2];
        __builtin_amdgcn_global_load_lds((const GLOBAL_AS unsigned int*)g,
                                         (LDS_AS unsigned int*)d, 16, 0, AUX);
    }
}

// ---------------- projection GEMM ----------------
__global__ void proj_gemm(const float* __restrict__ A, const float* __restrict__ W,
                          const float* __restrict__ bias, float* __restrict__ C) {
    __shared__ float As[64][33];
    __shared__ float Ws[64][33];
    const int bn = blockIdx.x * 64, bc = blockIdx.y * 64;
    const int tx = threadIdx.x & 15, ty = threadIdx.x >> 4;
    float acc[4][4] = {};
    for (int k0 = 0; k0 < 512; k0 += 32) {
#pragma unroll
        for (int l = 0; l < 2; ++l) {
            int f4 = threadIdx.x + l * 256;
            int row = f4 >> 3;
            int kk = (f4 & 7) << 2;
            float4 av = *(const float4*)&A[(size_t)(bn + row) * 512 + k0 + kk];
            float4 wv = *(const float4*)&W[(size_t)(bc + row) * 512 + k0 + kk];
            As[row][kk] = av.x; As[row][kk + 1] = av.y; As[row][kk + 2] = av.z; As[row][kk + 3] = av.w;
            Ws[row][kk] = wv.x; Ws[row][kk + 1] = wv.y; Ws[row][kk + 2] = wv.z; Ws[row][kk + 3] = wv.w;
        }
        __syncthreads();
#pragma unroll
        for (int kk = 0; kk < 32; ++kk) {
            float a0 = As[ty * 4 + 0][kk], a1 = As[ty * 4 + 1][kk], a2 = As[ty * 4 + 2][kk], a3 = As[ty * 4 + 3][kk];
            float w0 = Ws[tx * 4 + 0][kk], w1 = Ws[tx * 4 + 1][kk], w2 = Ws[tx * 4 + 2][kk], w3 = Ws[tx * 4 + 3][kk];
            acc[0][0] += a0 * w0; acc[0][1] += a0 * w1; acc[0][2] += a0 * w2; acc[0][3] += a0 * w3;
            acc[1][0] += a1 * w0; acc[1][1] += a1 * w1; acc[1][2] += a1 * w2; acc[1][3] += a1 * w3;
            acc[2][0] += a2 * w0; acc[2][1] += a2 * w1; acc[2][2] += a2 * w2; acc[2][3] += a2 * w3;
            acc[3][0] += a3 * w0; acc[3][1] += a3 * w1; acc[3][2] += a3 * w2; acc[3][3] += a3 * w3;
        }
        __syncthreads();
    }
    float4 bvv = *(const float4*)&bias[bc + tx * 4];
#pragma unroll
    for (int i = 0; i < 4; ++i) {
        float4 o = make_float4(acc[i][0] + bvv.x, acc[i][1] + bvv.y, acc[i][2] + bvv.z, acc[i][3] + bvv.w);
        *(float4*)&C[(size_t)(bn + ty * 4 + i) * 512 + bc + tx * 4] = o;
    }
}

// ---------------- depthwise conv ----------------
__global__ void conv_kernel(const float* __restrict__ P, const float* __restrict__ cw,
                            const float* __restrict__ cb, float* __restrict__ O) {
    int idx = blockIdx.x * 256 + threadIdx.x;
    if (idx >= 1024 * 32 * 128) return;
    int c4 = (idx & 127) << 2;
    int sb = idx >> 7;
    int s = sb >> 5, b = sb & 31;
    float acc0 = cb[c4 + 0], acc1 = cb[c4 + 1], acc2 = cb[c4 + 2], acc3 = cb[c4 + 3];
#pragma unroll
    for (int d = 0; d < 3; ++d) {
        int s2 = s + d - 1;
        if (s2 < 0 || s2 >= 1024) continue;
        float4 pv = *(const float4*)&P[((size_t)s2 * 32 + b) * 512 + c4];
        acc0 += pv.x * cw[(c4 + 0) * 3 + d];
        acc1 += pv.y * cw[(c4 + 1) * 3 + d];
        acc2 += pv.z * cw[(c4 + 2) * 3 + d];
        acc3 += pv.w * cw[(c4 + 3) * 3 + d];
    }
    *(float4*)&O[(size_t)sb * 512 + c4] = make_float4(acc0, acc1, acc2, acc3);
}

// ---------------- per-step scalars ----------------
__global__ void scalars_kernel(const float* __restrict__ x,
                               const float* __restrict__ aw, const float* __restrict__ ab,
                               const float* __restrict__ ew, const float* __restrict__ eb,
                               const float* __restrict__ tw, const float* __restrict__ tb,
                               float* __restrict__ scal) {
    const int t = blockIdx.x, tid = threadIdx.x;
    const int b = tid >> 3, part = tid & 7;
    const float* xp = x + ((size_t)t * 32 + b) * 512 + part * 64;
    float sa = 0.f, se = 0.f, st = 0.f;
    for (int i = 0; i < 64; i += 4) {
        float4 xv = *(const float4*)&xp[i];
        float4 av = *(const float4*)&aw[part * 64 + i];
        float4 ev = *(const float4*)&ew[part * 64 + i];
        float4 tv = *(const float4*)&tw[part * 64 + i];
        sa += xv.x * av.x + xv.y * av.y + xv.z * av.z + xv.w * av.w;
        se += xv.x * ev.x + xv.y * ev.y + xv.z * ev.z + xv.w * ev.w;
        st += xv.x * tv.x + xv.y * tv.y + xv.z * tv.z + xv.w * tv.w;
    }
#pragma unroll
    for (int m = 1; m < 8; m <<= 1) {
        sa += __shfl_xor(sa, m);
        se += __shfl_xor(se, m);
        st += __shfl_xor(st, m);
    }
    __shared__ float ra[32], re[32], rt[32];
    if (part == 0) {
        ra[b] = sigm_(sa + ab[0]);
        re[b] = sigm_(se + eb[0]);
        float z = st + tb[0];
        rt[b] = fmaxf(z, 0.f) + log1pf(expf(-fabsf(z)));
    }
    __syncthreads();
    if (tid == 0) { float s = 0.f; for (int i = 0; i < 32; ++i) s += ra[i]; scal[t] = s / 32.f; }
    if (tid == 1) { float s = 0.f; for (int i = 0; i < 32; ++i) s += re[i]; scal[1024 + t] = s / 32.f; }
    if (tid == 2) { float s = 0.f; for (int i = 0; i < 32; ++i) s += rt[i]; scal[2048 + t] = s / 32.f; }
}

// ---------------- l2-normalize K,Q ----------------
__global__ void l2norm_kernel(float* __restrict__ Kb, float* __restrict__ Qb) {
    int w = (blockIdx.x * 256 + threadIdx.x) >> 6;
    int lane = threadIdx.x & 63;
    if (w >= 2 * 32768) return;
    float* row = (w < 32768) ? (Kb + (size_t)w * 512) : (Qb + (size_t)(w - 32768) * 512);
    float4 v0 = *(float4*)&row[lane * 8];
    float4 v1 = *(float4*)&row[lane * 8 + 4];
    float ss = v0.x * v0.x + v0.y * v0.y + v0.z * v0.z + v0.w * v0.w
             + v1.x * v1.x + v1.y * v1.y + v1.z * v1.z + v1.w * v1.w;
#pragma unroll
    for (int m = 1; m < 64; m <<= 1) ss += __shfl_xor(ss, m);
    float inv = 1.f / fmaxf(sqrtf(ss), 1e-12f);
    v0.x *= inv; v0.y *= inv; v0.z *= inv; v0.w *= inv;
    v1.x *= inv; v1.y *= inv; v1.z *= inv; v1.w *= inv;
    *(float4*)&row[lane * 8] = v0;
    *(float4*)&row[lane * 8 + 4] = v1;
}

// ---------------- TTT scan: 512 threads, dbuf coherent DMA, split barrier ----------------
// Buffer discipline per step: buf2: h2G(t-1) -> K(t) (pre-issued under bar2) -> K(t+1).
// hbuf: h(t) -> dp(t) -> Q(t).
__global__ void __launch_bounds__(NTHR, 1) scan_kernel(
    const float* __restrict__ Kn, const float* __restrict__ Vv, const float* __restrict__ Qn,
    const float* __restrict__ scal,
    const float* __restrict__ MW1_0, const float* __restrict__ Mb1_0,
    const float* __restrict__ MW2_0, const float* __restrict__ Mb2_0,
    float* __restrict__ hG, float* __restrict__ dpG, float* __restrict__ h2G,
    float* __restrict__ outp, unsigned* __restrict__ bar) {
    const int g = blockIdx.x;
    const int tid = threadIdx.x;
    const int j0 = g * 2;
    unsigned ep = 0;

    __shared__ float W1[2][512], SW1[2][512];
    __shared__ float W2[2][512], SW2[2][512];
    __shared__ float W2T[2][512], SW2T[2][512];
    __shared__ float hbuf[32][516];                 // buffer A
    __shared__ float buf2[32][516];                 // buffer B
    __shared__ float red[8][32][2], red2[8][32][2];
    __shared__ float dpl[32][2], dzl[32][2], hj[32][2], hjp[32][2];
    __shared__ float bv1[2], Sb1[2], bv2[2], Sb2[2];

    for (int c = tid; c < 512; c += NTHR) {
#pragma unroll
        for (int r = 0; r < 2; ++r) {
            W1[r][c] = MW1_0[(size_t)(j0 + r) * 512 + c];
            W2[r][c] = MW2_0[(size_t)(j0 + r) * 512 + c];
            W2T[r][c] = MW2_0[(size_t)c * 512 + (j0 + r)];
            SW1[r][c] = 0.f; SW2[r][c] = 0.f; SW2T[r][c] = 0.f;
        }
    }
    if (tid < 2) { bv1[tid] = Mb1_0[j0 + tid]; Sb1[tid] = 0.f; bv2[tid] = Mb2_0[j0 + tid]; Sb2[tid] = 0.f; }
    __syncthreads();
    // h(0) = silu(ktn(0) @ W1.T + b1)
    {
        const int b = tid & 31, r = (tid >> 5) & 1, q = tid >> 6;   // q 0..7
        const float* kt = Kn + (size_t)b * 512;
        float p = 0.f;
        for (int i = q * 64; i < q * 64 + 64; i += 4) {
            float4 kv = *(const float4*)&kt[i];
            p += kv.x * W1[r][i] + kv.y * W1[r][i + 1] + kv.z * W1[r][i + 2] + kv.w * W1[r][i + 3];
        }
        red[q][b][r] = p;
    }
    __syncthreads();
    if (tid < 64) {
        const int b = tid & 31, r = tid >> 5;
        float z = bv1[r];
#pragma unroll
        for (int q = 0; q < 8; ++q) z += red[q][b][r];
        hjp[b][r] = z;
        float hh = z * sigm_(z);
        hj[b][r] = hh;
        coh_store(&hG[b * 512 + j0 + r], hh);
    }
    __syncthreads();
    ++ep; gbar_arrive(bar, ep); gbar_wait(bar, ep);

    for (int t = 0; t < 1024; ++t) {
        const float alpha = scal[t], eta = scal[1024 + t], theta = scal[2048 + t];
        // ======== phase A ========
        float vpre = 0.f;
        if (tid < 64) vpre = Vv[((size_t)t * 32 + (tid & 31)) * 512 + j0 + (tid >> 5)];
        stage_dma<17>(hG, hbuf, tid);               // h(t)  -> A (coherent)
        stage_dma<17>(h2G, buf2, tid);              // h2(t-1) -> B (garbage at t=0, unused)
        VMCNT0(); __syncthreads();
        {
            const int b = tid & 31, q = (tid >> 5) & 7;
            float p0 = 0.f, p1 = 0.f;
            if (tid < 256) {                        // pred partials from A
                for (int j = q * 64; j < q * 64 + 64; j += 4) {
                    float4 hv = *(const float4*)&hbuf[b][j];
                    p0 += hv.x * W2[0][j] + hv.y * W2[0][j + 1] + hv.z * W2[0][j + 2] + hv.w * W2[0][j + 3];
                    p1 += hv.x * W2[1][j] + hv.y * W2[1][j + 1] + hv.z * W2[1][j + 2] + hv.w * W2[1][j + 3];
                }
                red[q][b][0] = p0; red[q][b][1] = p1;
            } else if (t > 0) {                     // out[t-1] partials from B
                for (int j = q * 64; j < q * 64 + 64; j += 4) {
                    float4 hv = *(const float4*)&buf2[b][j];
                    p0 += hv.x * W2[0][j] + hv.y * W2[0][j + 1] + hv.z * W2[0][j + 2] + hv.w * W2[0][j + 3];
                    p1 += hv.x * W2[1][j] + hv.y * W2[1][j + 1] + hv.z * W2[1][j + 2] + hv.w * W2[1][j + 3];
                }
                red2[q][b][0] = p0; red2[q][b][1] = p1;
            }
        }
        __syncthreads();
        if (tid < 64) {
            const int b = tid & 31, o = tid >> 5;
            float pred = bv2[o];
#pragma unroll
            for (int q = 0; q < 8; ++q) pred += red[q][b][o];
            float dp = (pred - vpre) * (2.f / 16384.f);
            dpl[b][o] = dp;
            coh_store(&dpG[b * 512 + j0 + o], dp);
        } else if (tid < 128) {
            if (t > 0) {
                const int b = tid & 31, o = (tid >> 5) & 1;
                float ov = bv2[o];
#pragma unroll
                for (int q = 0; q < 8; ++q) ov += red2[q][b][o];
                outp[((size_t)(t - 1) * 32 + b) * 512 + j0 + o] = ov;
            }
        }
        __syncthreads();
        ++ep; gbar_arrive(bar, ep);                 // dp published
        stage_dma<0>(Kn + (size_t)t * 16384, buf2, tid);   // K(t) -> B, flies under bar2
        if (tid < 2) {                              // b2 update (hidden)
            float db2 = 0.f;
            for (int b = 0; b < 32; ++b) db2 += dpl[b][tid];
            float s = eta * Sb2[tid] - theta * db2;
            Sb2[tid] = s;
            bv2[tid] = (1.f - alpha) * bv2[tid] + s;
        }
        {                                           // dW2 update (hidden)
            const int j = tid;
            float d00 = 0.f, d10 = 0.f;
            for (int b = 0; b < 32; ++b) {
                float h0 = hbuf[b][j];
                d00 += dpl[b][0] * h0;
                d10 += dpl[b][1] * h0;
            }
            float s;
            s = eta * SW2[0][j] - theta * d00; SW2[0][j] = s; W2[0][j] = (1.f - alpha) * W2[0][j] + s;
            s = eta * SW2[1][j] - theta * d10; SW2[1][j] = s; W2[1][j] = (1.f - alpha) * W2[1][j] + s;
        }
        gbar_wait(bar, ep);

        // ======== phase B ========
        stage_dma<17>(dpG, hbuf, tid);              // dp -> A (coherent)
        VMCNT0(); __syncthreads();                  // dp + K(t) both landed
        {
            const int b = tid & 31, r = (tid >> 5) & 1, q = tid >> 6;
            float p = 0.f;
            for (int o = q * 64; o < q * 64 + 64; o += 4) {
                float4 dv = *(const float4*)&hbuf[b][o];
                p += dv.x * W2T[r][o] + dv.y * W2T[r][o + 1] + dv.z * W2T[r][o + 2] + dv.w * W2T[r][o + 3];
            }
            red[q][b][r] = p;
        }
        __syncthreads();
        if (tid < 64) {
            const int b = tid & 31, r = tid >> 5;
            float dh = 0.f;
#pragma unroll
            for (int q = 0; q < 8; ++q) dh += red[q][b][r];
            float z = hjp[b][r];
            float sg = sigm_(z);
            dzl[b][r] = dh * (sg * (1.f + z * (1.f - sg)));
        }
        __syncthreads();
        if (tid < 2) {                              // b1 update
            float db1 = 0.f;
            for (int b = 0; b < 32; ++b) db1 += dzl[b][tid];
            float s = eta * Sb1[tid] - theta * db1;
            Sb1[tid] = s;
            bv1[tid] = (1.f - alpha) * bv1[tid] + s;
        }
        {                                           // dW2T update
            const int o = tid;
            float d00 = 0.f, d10 = 0.f;
            for (int b = 0; b < 32; ++b) {
                float q0 = hbuf[b][o];
                d00 += hj[b][0] * q0;
                d10 += hj[b][1] * q0;
            }
            float s;
            s = eta * SW2T[0][o] - theta * d00; SW2T[0][o] = s; W2T[0][o] = (1.f - alpha) * W2T[0][o] + s;
            s = eta * SW2T[1][o] - theta * d10; SW2T[1][o] = s; W2T[1][o] = (1.f - alpha) * W2T[1][o] + s;
        }
        __syncthreads();                            // A reads done
        stage_dma<0>(Qn + (size_t)t * 16384, hbuf, tid);   // Q(t) -> A, flies over dW1
        {                                           // dW1 update (reads B=K, dzl)
            const int c = tid;
            float d00 = 0.f, d10 = 0.f;
            for (int b = 0; b < 32; ++b) {
                float k0 = buf2[b][c];
                d00 += dzl[b][0] * k0;
                d10 += dzl[b][1] * k0;
            }
            float s;
            s = eta * SW1[0][c] - theta * d00; SW1[0][c] = s; W1[0][c] = (1.f - alpha) * W1[0][c] + s;
            s = eta * SW1[1][c] - theta * d10; SW1[1][c] = s; W1[1][c] = (1.f - alpha) * W1[1][c] + s;
        }
        __syncthreads();                            // B reads done
        if (t < 1023) {
            stage_dma<0>(Kn + (size_t)(t + 1) * 16384, buf2, tid);  // K(t+1) -> B
            VMCNT8();                               // Q ready (oldest 8), K2 flying
        } else {
            VMCNT0();                               // Q ready
        }
        __syncthreads();
        {                                           // GEMM4: h2 partials from Q(A)
            const int b = tid & 31, r = (tid >> 5) & 1, q = tid >> 6;
            float p = 0.f;
            for (int i = q * 64; i < q * 64 + 64; i += 4) {
                float4 qv2 = *(const float4*)&hbuf[b][i];
                p += qv2.x * W1[r][i] + qv2.y * W1[r][i + 1] + qv2.z * W1[r][i + 2] + qv2.w * W1[r][i + 3];
            }
            red[q][b][r] = p;
        }
        VMCNT0();                                   // K2 landed (own wave)
        __syncthreads();                            // all waves' K2 landed
        if (t < 1023) {                             // GEMM1: h(t+1) partials from K2(B)
            const int b = tid & 31, r = (tid >> 5) & 1, q = tid >> 6;
            float p = 0.f;
            for (int i = q * 64; i < q * 64 + 64; i += 4) {
                float4 kv2 = *(const float4*)&buf2[b][i];
                p += kv2.x * W1[r][i] + kv2.y * W1[r][i + 1] + kv2.z * W1[r][i + 2] + kv2.w * W1[r][i + 3];
            }
            red2[q][b][r] = p;
        }
        __syncthreads();
        if (tid < 64) {
            const int b = tid & 31, r = tid >> 5;
            float z2 = bv1[r];
#pragma unroll
            for (int q = 0; q < 8; ++q) z2 += red[q][b][r];
            coh_store(&h2G[b * 512 + j0 + r], z2 * sigm_(z2));
            if (t < 1023) {
                float z = bv1[r];
#pragma unroll
                for (int q = 0; q < 8; ++q) z += red2[q][b][r];
                hjp[b][r] = z;
                float hh = z * sigm_(z);
                hj[b][r] = hh;
                coh_store(&hG[b * 512 + j0 + r], hh);
            }
        }
        // no sync: producer stores + arrive are both wave 0 (sequential);
        // cross-wave consumers of hj/hjp are ordered by gbar_wait's barrier.
        ++ep; gbar_arrive(bar, ep); gbar_wait(bar, ep);
    }

    // ---- epilogue: out[1023] = h2(1023) @ W2(1023).T + b2(1023) ----
    stage_dma<17>(h2G, hbuf, tid);
    VMCNT0(); __syncthreads();
    if (tid < 256) {
        const int b = tid & 31, q = (tid >> 5) & 7;
        float p0 = 0.f, p1 = 0.f;
        for (int j = q * 64; j < q * 64 + 64; j += 4) {
            float4 hv = *(const float4*)&hbuf[b][j];
            p0 += hv.x * W2[0][j] + hv.y * W2[0][j + 1] + hv.z * W2[0][j + 2] + hv.w * W2[0][j + 3];
            p1 += hv.x * W2[1][j] + hv.y * W2[1][j + 1] + hv.z * W2[1][j + 2] + hv.w * W2[1][j + 3];
        }
        red[q][b][0] = p0; red[q][b][1] = p1;
    }
    __syncthreads();
    if (tid < 64) {
        const int b = tid & 31, o = tid >> 5;
        float ov = bv2[o];
#pragma unroll
        for (int q = 0; q < 8; ++q) ov += red[q][b][o];
        outp[((size_t)1023 * 32 + b) * 512 + j0 + o] = ov;
    }
}

extern "C" void kernel_launch(void* const* d_in, const int* in_sizes, int n_in,
                              void* d_out, int out_size, void* d_ws, size_t ws_size,
                              hipStream_t stream) {
    (void)in_sizes; (void)n_in; (void)out_size; (void)ws_size;
    const float* x    = (const float*)d_in[0];
    const float* Wk_w = (const float*)d_in[1];
    const float* Wk_b = (const float*)d_in[2];
    const float* Wv_w = (const float*)d_in[3];
    const float* Wv_b = (const float*)d_in[4];
    const float* Wq_w = (const float*)d_in[5];
    const float* Wq_b = (const float*)d_in[6];
    const float* ck_w = (const float*)d_in[7];
    const float* ck_b = (const float*)d_in[8];
    const float* cv_w = (const float*)d_in[9];
    const float* cv_b = (const float*)d_in[10];
    const float* cq_w = (const float*)d_in[11];
    const float* cq_b = (const float*)d_in[12];
    const float* MW1  = (const float*)d_in[13];
    const float* Mb1  = (const float*)d_in[14];
    const float* MW2  = (const float*)d_in[15];
    const float* Mb2  = (const float*)d_in[16];
    const float* a_w  = (const float*)d_in[17];
    const float* a_b  = (const float*)d_in[18];
    const float* e_w  = (const float*)d_in[19];
    const float* e_b  = (const float*)d_in[20];
    const float* t_w  = (const float*)d_in[21];
    const float* t_b  = (const float*)d_in[22];

    float* out = (float*)d_out;
    float* ws = (float*)d_ws;
    float* Kb   = ws;                    // [1024][32][512]
    float* Vb   = Kb + 16777216;
    float* Qb   = Vb + 16777216;
    float* scal = Qb + 16777216;         // [3][1024]
    float* hG   = scal + 3072;           // [32][512]
    float* dpG  = hG + 16384;
    float* h2G  = dpG + 16384;
    unsigned* bar = (unsigned*)(h2G + 16384);  // arr[256] + flag@320; memset 8KB
    float* tmp  = out;                   // reuse d_out as pre-conv scratch

    hipMemsetAsync(bar, 0, 8192, stream);
    scalars_kernel<<<1024, 256, 0, stream>>>(x, a_w, a_b, e_w, e_b, t_w, t_b, scal);
    proj_gemm<<<dim3(512, 8), 256, 0, stream>>>(x, Wk_w, Wk_b, tmp);
    conv_kernel<<<16384, 256, 0, stream>>>(tmp, ck_w, ck_b, Kb);
    proj_gemm<<<dim3(512, 8), 256, 0, stream>>>(x, Wv_w, Wv_b, tmp);
    conv_kernel<<<16384, 256, 0, stream>>>(tmp, cv_w, cv_b, Vb);
    proj_gemm<<<dim3(512, 8), 256, 0, stream>>>(x, Wq_w, Wq_b, tmp);
    conv_kernel<<<16384, 256, 0, stream>>>(tmp, cq_w, cq_b, Qb);
    l2norm_kernel<<<16384, 256, 0, stream>>>(Kb, Qb);

    const float *aKn = Kb, *aV = Vb, *aQn = Qb, *aSc = scal;
    const float *aW1 = MW1, *ab1 = Mb1, *aW2 = MW2, *ab2 = Mb2;
    float *ahG = hG, *adpG = dpG, *ah2G = h2G, *aout = out;
    unsigned* abar = bar;
    void* kargs[] = {(void*)&aKn, (void*)&aV, (void*)&aQn, (void*)&aSc,
                     (void*)&aW1, (void*)&ab1, (void*)&aW2, (void*)&ab2,
                     (void*)&ahG, (void*)&adpG, (void*)&ah2G, (void*)&aout, (void*)&abar};
    hipError_t ce = hipLaunchCooperativeKernel((void*)scan_kernel, dim3(NBLK), dim3(NTHR), kargs, 0, stream);
    if (ce != hipSuccess) {
        // Cooperative validation rejected the kernel; our barrier only needs co-residency
        // (grid == 256 CUs, ~158KB LDS forces 1 block/CU), so fall back to a regular launch.
        scan_kernel<<<dim3(NBLK), dim3(NTHR), 0, stream>>>(
            Kb, Vb, Qb, scal, MW1, Mb1, MW2, Mb2, hG, dpG, h2G, out, bar);
    }
}